// Round 1
// baseline (7648.212 us; speedup 1.0000x reference)
//
#include <hip/hip_runtime.h>
#include <cstdio>
#include <cstdint>

// ---------------- pre-pass kernels ----------------

__global__ void k_init_deg(float* __restrict__ deg, int N) {
  int i = blockIdx.x * blockDim.x + threadIdx.x;
  if (i < N) deg[i] = 1.0f;   // self-loop weight
}

__global__ void k_deg_acc(const int* __restrict__ dst, const float* __restrict__ ew,
                          float* __restrict__ deg, int E) {
  int e = blockIdx.x * blockDim.x + threadIdx.x;
  if (e < E) atomicAdd(&deg[dst[e]], ew[e]);
}

__global__ void k_dinv(const float* __restrict__ deg, float* __restrict__ dinv,
                       float* __restrict__ selfnorm, int N) {
  int i = blockIdx.x * blockDim.x + threadIdx.x;
  if (i < N) {
    float d = deg[i];
    float r = (d > 0.f) ? (float)(1.0 / sqrt((double)d)) : 0.f;
    dinv[i] = r;
    selfnorm[i] = r * r;
  }
}

__global__ void k_norm(const int* __restrict__ src, const int* __restrict__ dst,
                       const float* __restrict__ ew, const float* __restrict__ dinv,
                       float* __restrict__ nrm, int E) {
  int e = blockIdx.x * blockDim.x + threadIdx.x;
  if (e < E) nrm[e] = dinv[src[e]] * ew[e] * dinv[dst[e]];
}

__global__ void k_zero_pool(double* __restrict__ psum, float* __restrict__ cnt, int B, int C) {
  int i = blockIdx.x * blockDim.x + threadIdx.x;
  if (i < B * C) psum[i] = 0.0;
  if (i < B) cnt[i] = 0.f;
}

// ---------------- GEMM with fused input bias+relu and self-loop agg init ----------------
// X:[N,K] (optionally relu(X+bin) applied on load), W:[K,D].
// Writes H = act(X) @ W  and  AGG = H * selfnorm[row]  (self-loop contribution).
// Block tile 128x128, BK=32, 256 threads, 8x8 per-thread microtile.

__global__ __launch_bounds__(256)
void k_gemm_agg(const float* __restrict__ X, const float* __restrict__ W,
                const float* __restrict__ bin, const float* __restrict__ selfnorm,
                float* __restrict__ H, float* __restrict__ AGG,
                int N, int K, int D) {
  __shared__ float As[32][132];   // As[k][m], pad 4 keeps float4 alignment + ~conflict-free
  __shared__ float Bs[32][132];   // Bs[k][n]
  const int t  = threadIdx.x;
  const int m0 = blockIdx.y * 128;
  const int n0 = blockIdx.x * 128;
  const int ty = t >> 4, tx = t & 15;

  float acc[8][8];
#pragma unroll
  for (int i = 0; i < 8; i++)
#pragma unroll
    for (int j = 0; j < 8; j++) acc[i][j] = 0.f;

  const int alr = t >> 1, alc = (t & 1) << 4;   // A: 128 rows x 32 k, 16 floats/thread
  const int blr = t >> 3, blc = (t & 7) << 4;   // B: 32 rows  x 128 n, 16 floats/thread
  int gra = m0 + alr; if (gra >= N) gra = N - 1;  // clamp tail (value unused)

  for (int k0 = 0; k0 < K; k0 += 32) {
    {  // load A tile
      const float* ap = X + (size_t)gra * K + (k0 + alc);
      float av[16];
#pragma unroll
      for (int j4 = 0; j4 < 4; j4++) {
        float4 v = *reinterpret_cast<const float4*>(ap + 4 * j4);
        av[4*j4+0]=v.x; av[4*j4+1]=v.y; av[4*j4+2]=v.z; av[4*j4+3]=v.w;
      }
      if (bin) {
#pragma unroll
        for (int i = 0; i < 16; i++) av[i] = fmaxf(av[i] + bin[k0 + alc + i], 0.f);
      }
#pragma unroll
      for (int i = 0; i < 16; i++) As[alc + i][alr] = av[i];
    }
    {  // load B tile (guard cols for D < 128)
      const float* wp = W + (size_t)(k0 + blr) * D + n0;
#pragma unroll
      for (int j4 = 0; j4 < 4; j4++) {
        int n = blc + 4 * j4;
        float4 v;
        if (n0 + n < D) v = *reinterpret_cast<const float4*>(wp + n);
        else            v = make_float4(0.f, 0.f, 0.f, 0.f);
        *reinterpret_cast<float4*>(&Bs[blr][n]) = v;
      }
    }
    __syncthreads();
#pragma unroll
    for (int kk = 0; kk < 32; kk++) {
      float a[8], b[8];
      float4 t0 = *reinterpret_cast<const float4*>(&As[kk][ty * 8]);
      float4 t1 = *reinterpret_cast<const float4*>(&As[kk][ty * 8 + 4]);
      a[0]=t0.x; a[1]=t0.y; a[2]=t0.z; a[3]=t0.w; a[4]=t1.x; a[5]=t1.y; a[6]=t1.z; a[7]=t1.w;
      float4 u0 = *reinterpret_cast<const float4*>(&Bs[kk][tx * 8]);
      float4 u1 = *reinterpret_cast<const float4*>(&Bs[kk][tx * 8 + 4]);
      b[0]=u0.x; b[1]=u0.y; b[2]=u0.z; b[3]=u0.w; b[4]=u1.x; b[5]=u1.y; b[6]=u1.z; b[7]=u1.w;
#pragma unroll
      for (int i = 0; i < 8; i++)
#pragma unroll
        for (int j = 0; j < 8; j++) acc[i][j] = fmaf(a[i], b[j], acc[i][j]);
    }
    __syncthreads();
  }

#pragma unroll
  for (int i = 0; i < 8; i++) {
    int gm = m0 + ty * 8 + i;
    if (gm >= N) continue;
    float sn = selfnorm[gm];
#pragma unroll
    for (int j4 = 0; j4 < 2; j4++) {
      int gn = n0 + tx * 8 + 4 * j4;
      if (gn < D) {
        float4 hv = make_float4(acc[i][4*j4+0], acc[i][4*j4+1], acc[i][4*j4+2], acc[i][4*j4+3]);
        *reinterpret_cast<float4*>(H   + (size_t)gm * D + gn) = hv;
        float4 av = make_float4(hv.x * sn, hv.y * sn, hv.z * sn, hv.w * sn);
        *reinterpret_cast<float4*>(AGG + (size_t)gm * D + gn) = av;
      }
    }
  }
}

// ---------------- edge scatter: AGG[dst] += H[src] * norm ----------------
// L = D/4 lanes per edge, each lane handles one float4.

template<int LOG2L>
__global__ __launch_bounds__(256)
void k_scatter(const int* __restrict__ src, const int* __restrict__ dst,
               const float* __restrict__ nrm, const float* __restrict__ H,
               float* __restrict__ AGG, int E, int D) {
  int t = blockIdx.x * blockDim.x + threadIdx.x;
  int e = t >> LOG2L;
  if (e >= E) return;
  int c = (t & ((1 << LOG2L) - 1)) << 2;
  int s = src[e], d = dst[e];
  float w = nrm[e];
  const float4 v = *reinterpret_cast<const float4*>(H + (size_t)s * D + c);
  float* o = AGG + (size_t)d * D + c;
  atomicAdd(o + 0, v.x * w);
  atomicAdd(o + 1, v.y * w);
  atomicAdd(o + 2, v.z * w);
  atomicAdd(o + 3, v.w * w);
}

// ---------------- pooling (sorted protein_batch) ----------------
// Block = C=320 threads, each block handles 64 consecutive nodes; per-thread
// fp64 accumulator flushed on batch change. Cols 0..D3-1 read relu(AGG3+b3),
// cols D3.. read feature.

__global__ void k_pool(const float* __restrict__ AGG3, const float* __restrict__ b3,
                       const float* __restrict__ feat, const int* __restrict__ pb,
                       double* __restrict__ psum, int N, int D3, int F) {
  const int c = threadIdx.x;
  const int C = D3 + F;
  int i0 = blockIdx.x * 64;
  if (i0 >= N) return;
  int iend = i0 + 64; if (iend > N) iend = N;
  double acc = 0.0;
  int cur = pb[i0];
  float bias = (c < D3) ? b3[c] : 0.f;
  for (int i = i0; i < iend; i++) {
    int b = pb[i];
    if (b != cur) {
      atomicAdd(&psum[(size_t)cur * C + c], acc);
      acc = 0.0; cur = b;
    }
    float v;
    if (c < D3) v = fmaxf(AGG3[(size_t)i * D3 + c] + bias, 0.f);
    else        v = feat[(size_t)i * F + (c - D3)];
    acc += (double)v;
  }
  atomicAdd(&psum[(size_t)cur * C + c], acc);
}

__global__ void k_count(const int* __restrict__ pb, float* __restrict__ cnt, int N) {
  int tchunk = blockIdx.x * blockDim.x + threadIdx.x;
  int i0 = tchunk * 64;
  if (i0 >= N) return;
  int iend = i0 + 64; if (iend > N) iend = N;
  float cacc = 0.f; int cur = pb[i0];
  for (int i = i0; i < iend; i++) {
    int b = pb[i];
    if (b != cur) { atomicAdd(&cnt[cur], cacc); cacc = 0.f; cur = b; }
    cacc += 1.f;
  }
  atomicAdd(&cnt[cur], cacc);
}

// ---------------- FC head ----------------

__global__ __launch_bounds__(256)
void k_fc1(const double* __restrict__ psum, const float* __restrict__ cnt,
           const float* __restrict__ Wf1, const float* __restrict__ bf1,
           float* __restrict__ hidden, int C, int Hh) {
  int b = blockIdx.x;
  int t = threadIdx.x;
  __shared__ float gcs[512];
  float invc = 1.f / fmaxf(cnt[b], 1.f);
  for (int c = t; c < C; c += blockDim.x)
    gcs[c] = (float)psum[(size_t)b * C + c] * invc;
  __syncthreads();
  for (int j = t; j < Hh; j += blockDim.x) {
    double s = 0.0;
    for (int c = 0; c < C; c++) s += (double)gcs[c] * (double)Wf1[(size_t)c * Hh + j];
    float r = (float)s + bf1[j];
    hidden[(size_t)b * Hh + j] = fmaxf(r, 0.f);
  }
}

__global__ void k_fc2(const float* __restrict__ hidden, const float* __restrict__ Wf2,
                      const float* __restrict__ bf2, float* __restrict__ out, int Hh) {
  int b = blockIdx.x;
  int lane = threadIdx.x;  // 64
  double s = 0.0;
  for (int j = lane; j < Hh; j += 64) s += (double)hidden[(size_t)b * Hh + j] * (double)Wf2[j];
#pragma unroll
  for (int off = 32; off > 0; off >>= 1) s += __shfl_down(s, off);
  if (lane == 0) out[b] = (float)s + bf2[0];
}

// ---------------- launch ----------------

extern "C" void kernel_launch(void* const* d_in, const int* in_sizes, int n_in,
                              void* d_out, int out_size, void* d_ws, size_t ws_size,
                              hipStream_t stream) {
  const float* feature = (const float*)d_in[0];
  const int*   eidx    = (const int*)  d_in[1];
  const float* weight  = (const float*)d_in[2];
  const int*   pb      = (const int*)  d_in[3];
  const float* W1  = (const float*)d_in[4];
  const float* b1  = (const float*)d_in[5];
  const float* W2  = (const float*)d_in[6];
  const float* b2  = (const float*)d_in[7];
  const float* W3  = (const float*)d_in[8];
  const float* b3  = (const float*)d_in[9];
  const float* Wf1 = (const float*)d_in[10];
  const float* bf1 = (const float*)d_in[11];
  const float* Wf2 = (const float*)d_in[12];
  const float* bf2 = (const float*)d_in[13];

  const int F  = in_sizes[5];          // 64
  const int D2 = in_sizes[7];          // 128
  const int D3 = in_sizes[9];          // 256
  const int Hh = in_sizes[11];         // 1024
  const int N  = in_sizes[0] / F;      // 100000
  const int E  = in_sizes[1] / 2;      // 1200000
  const int B  = out_size;             // 256 (O==1)
  const int C  = D3 + F;               // 320

  const int* srcp = eidx;
  const int* dstp = eidx + E;

  auto al = [](size_t x) { return (x + 255) & ~(size_t)255; };
  size_t off = 0;
  auto alloc = [&](size_t bytes) { size_t o = off; off += al(bytes); return o; };
  size_t o_deg   = alloc((size_t)N * 4);
  size_t o_dinv  = alloc((size_t)N * 4);
  size_t o_sn    = alloc((size_t)N * 4);
  size_t o_norm  = alloc((size_t)E * 4);
  size_t o_h     = alloc((size_t)N * D3 * 4);   // h (widest layer)
  size_t o_aggA  = alloc((size_t)N * D3 * 4);   // agg1 (first N*F) and agg3 alias here
  size_t o_agg2  = alloc((size_t)N * D2 * 4);
  size_t o_psum  = alloc((size_t)B * C * 8);
  size_t o_cnt   = alloc((size_t)B * 4);
  size_t o_hid   = alloc((size_t)B * Hh * 4);
  if (off > ws_size) {
    fprintf(stderr, "kernel_launch: workspace too small: need %zu, have %zu\n", off, ws_size);
    return;
  }

  char* ws = (char*)d_ws;
  float*  deg   = (float*)(ws + o_deg);
  float*  dinv  = (float*)(ws + o_dinv);
  float*  sn    = (float*)(ws + o_sn);
  float*  nrm   = (float*)(ws + o_norm);
  float*  hbuf  = (float*)(ws + o_h);
  float*  aggA  = (float*)(ws + o_aggA);
  float*  agg2  = (float*)(ws + o_agg2);
  double* psum  = (double*)(ws + o_psum);
  float*  cnt   = (float*)(ws + o_cnt);
  float*  hid   = (float*)(ws + o_hid);
  float*  out   = (float*)d_out;

  // pre-pass
  k_init_deg<<<(N + 255) / 256, 256, 0, stream>>>(deg, N);
  k_deg_acc <<<(E + 255) / 256, 256, 0, stream>>>(dstp, weight, deg, E);
  k_dinv    <<<(N + 255) / 256, 256, 0, stream>>>(deg, dinv, sn, N);
  k_norm    <<<(E + 255) / 256, 256, 0, stream>>>(srcp, dstp, weight, dinv, nrm, E);
  k_zero_pool<<<(B * C + 255) / 256, 256, 0, stream>>>(psum, cnt, B, C);

  // layer 1: feature[N,F] @ W1[F,F]
  {
    dim3 g((F + 127) / 128, (N + 127) / 128);
    k_gemm_agg<<<g, 256, 0, stream>>>(feature, W1, nullptr, sn, hbuf, aggA, N, F, F);
    int total = E << 4;  // F/4 == 16 lanes
    k_scatter<4><<<(total + 255) / 256, 256, 0, stream>>>(srcp, dstp, nrm, hbuf, aggA, E, F);
  }
  // layer 2: relu(agg1+b1)[N,F] @ W2[F,D2]
  {
    dim3 g((D2 + 127) / 128, (N + 127) / 128);
    k_gemm_agg<<<g, 256, 0, stream>>>(aggA, W2, b1, sn, hbuf, agg2, N, F, D2);
    int total = E << 5;  // D2/4 == 32 lanes
    k_scatter<5><<<(total + 255) / 256, 256, 0, stream>>>(srcp, dstp, nrm, hbuf, agg2, E, D2);
  }
  // layer 3: relu(agg2+b2)[N,D2] @ W3[D2,D3]
  {
    dim3 g((D3 + 127) / 128, (N + 127) / 128);
    k_gemm_agg<<<g, 256, 0, stream>>>(agg2, W3, b2, sn, hbuf, aggA, N, D2, D3);
    int total = E << 6;  // D3/4 == 64 lanes
    k_scatter<6><<<(total + 255) / 256, 256, 0, stream>>>(srcp, dstp, nrm, hbuf, aggA, E, D3);
  }

  // pooling + head
  k_count<<<((N + 63) / 64 + 255) / 256, 256, 0, stream>>>(pb, cnt, N);
  k_pool <<<(N + 63) / 64, C, 0, stream>>>(aggA, b3, feature, pb, psum, N, D3, F);
  k_fc1  <<<B, 256, 0, stream>>>(psum, cnt, Wf1, bf1, hid, C, Hh);
  k_fc2  <<<B, 64, 0, stream>>>(hid, Wf2, bf2, out, Hh);
}

// Round 2
// 898.380 us; speedup vs baseline: 8.5133x; 8.5133x over previous
//
#include <hip/hip_runtime.h>
#include <cstdio>
#include <cstdint>

// ================= pre-pass: degree, norms, CSR build =================

__global__ void k_init(float* __restrict__ deg, int* __restrict__ cnt,
                       int* __restrict__ fill, int N) {
  int i = blockIdx.x * blockDim.x + threadIdx.x;
  if (i < N) { deg[i] = 1.0f; cnt[i] = 0; fill[i] = 0; }  // deg starts at self-loop weight
}

__global__ void k_edge_count(const int* __restrict__ dst, const float* __restrict__ ew,
                             float* __restrict__ deg, int* __restrict__ cnt, int E) {
  int e = blockIdx.x * blockDim.x + threadIdx.x;
  if (e < E) {
    int d = dst[e];
    atomicAdd(&deg[d], ew[e]);
    atomicAdd(&cnt[d], 1);
  }
}

__global__ void k_dinv(const float* __restrict__ deg, float* __restrict__ dinv,
                       float* __restrict__ selfnorm, int N) {
  int i = blockIdx.x * blockDim.x + threadIdx.x;
  if (i < N) {
    float d = deg[i];
    float r = (d > 0.f) ? (float)(1.0 / sqrt((double)d)) : 0.f;
    dinv[i] = r;
    selfnorm[i] = r * r;
  }
}

// exclusive scan of cnt[N] -> rs[N]; 1024 elems / block (256 thr x 4)
__global__ __launch_bounds__(256)
void k_scan1(const int* __restrict__ cnt, int* __restrict__ rs,
             int* __restrict__ bsum, int N) {
  __shared__ int sh[256];
  const int t = threadIdx.x;
  const int base = blockIdx.x * 1024;
  int v[4]; int s = 0;
#pragma unroll
  for (int j = 0; j < 4; j++) {
    int idx = base + t * 4 + j;
    v[j] = (idx < N) ? cnt[idx] : 0;
    s += v[j];
  }
  sh[t] = s;
  __syncthreads();
  for (int off = 1; off < 256; off <<= 1) {
    int x = (t >= off) ? sh[t - off] : 0;
    __syncthreads();
    sh[t] += x;
    __syncthreads();
  }
  int run = sh[t] - s;  // exclusive prefix of this thread's chunk
#pragma unroll
  for (int j = 0; j < 4; j++) {
    int idx = base + t * 4 + j;
    if (idx < N) rs[idx] = run;
    run += v[j];
  }
  if (t == 255) bsum[blockIdx.x] = sh[255];
}

__global__ void k_scan2(int* __restrict__ bsum, int nb) {
  if (blockIdx.x == 0 && threadIdx.x == 0) {
    int run = 0;
    for (int i = 0; i < nb; i++) { int v = bsum[i]; bsum[i] = run; run += v; }
  }
}

__global__ void k_scan3(int* __restrict__ rs, const int* __restrict__ bsum, int N) {
  int i = blockIdx.x * blockDim.x + threadIdx.x;
  if (i < N) rs[i] += bsum[i >> 10];
}

// place each edge into its dst row: epack[pos] = {src, norm}
__global__ void k_csr_fill(const int* __restrict__ src, const int* __restrict__ dst,
                           const float* __restrict__ ew, const float* __restrict__ dinv,
                           const int* __restrict__ rs, int* __restrict__ fill,
                           int2* __restrict__ epack, int E) {
  int e = blockIdx.x * blockDim.x + threadIdx.x;
  if (e >= E) return;
  int d = dst[e], s = src[e];
  int pos = rs[d] + atomicAdd(&fill[d], 1);
  float w = dinv[s] * ew[e] * dinv[d];
  epack[pos] = make_int2(s, __float_as_int(w));
}

__global__ void k_zero_pool(double* __restrict__ psum, float* __restrict__ cnt, int B, int C) {
  int i = blockIdx.x * blockDim.x + threadIdx.x;
  if (i < B * C) psum[i] = 0.0;
  if (i < B) cnt[i] = 0.f;
}

// ================= CSR gather aggregation: AGG = Â @ X =================
// One thread per (row, float4-col). Lanes of a row read 256B coalesced
// chunks of X[src]; output written once, coalesced; zero atomics.

template<int LOG2D4>
__global__ __launch_bounds__(256)
void k_aggregate(const float* __restrict__ X, const int* __restrict__ rs,
                 const int* __restrict__ cntn, const int2* __restrict__ epack,
                 const float* __restrict__ sn, float* __restrict__ AGG, int N) {
  const int t = blockIdx.x * blockDim.x + threadIdx.x;
  const int row = t >> LOG2D4;
  if (row >= N) return;
  const int D4 = 1 << LOG2D4;
  const int D = D4 << 2;
  const int c = (t & (D4 - 1)) << 2;

  float4 acc = *reinterpret_cast<const float4*>(X + (size_t)row * D + c);
  float s = sn[row];
  acc.x *= s; acc.y *= s; acc.z *= s; acc.w *= s;

  const int p0 = rs[row];
  const int k = cntn[row];
  for (int i = 0; i < k; i++) {
    int2 e = epack[p0 + i];
    float w = __int_as_float(e.y);
    const float4 v = *reinterpret_cast<const float4*>(X + (size_t)e.x * D + c);
    acc.x = fmaf(v.x, w, acc.x);
    acc.y = fmaf(v.y, w, acc.y);
    acc.z = fmaf(v.z, w, acc.z);
    acc.w = fmaf(v.w, w, acc.w);
  }
  *reinterpret_cast<float4*>(AGG + (size_t)row * D + c) = acc;
}

// ================= GEMM: Y = relu(X @ W + b) =================
// 128x128 tile, BK=32, 256 threads, 8x8 microtile.

__global__ __launch_bounds__(256)
void k_gemm_bre(const float* __restrict__ X, const float* __restrict__ W,
                const float* __restrict__ bout, float* __restrict__ Y,
                int N, int K, int D) {
  __shared__ float As[32][132];
  __shared__ float Bs[32][132];
  const int t  = threadIdx.x;
  const int m0 = blockIdx.y * 128;
  const int n0 = blockIdx.x * 128;
  const int ty = t >> 4, tx = t & 15;

  float acc[8][8];
#pragma unroll
  for (int i = 0; i < 8; i++)
#pragma unroll
    for (int j = 0; j < 8; j++) acc[i][j] = 0.f;

  const int alr = t >> 1, alc = (t & 1) << 4;
  const int blr = t >> 3, blc = (t & 7) << 4;
  int gra = m0 + alr; if (gra >= N) gra = N - 1;

  for (int k0 = 0; k0 < K; k0 += 32) {
    {
      const float* ap = X + (size_t)gra * K + (k0 + alc);
      float av[16];
#pragma unroll
      for (int j4 = 0; j4 < 4; j4++) {
        float4 v = *reinterpret_cast<const float4*>(ap + 4 * j4);
        av[4*j4+0]=v.x; av[4*j4+1]=v.y; av[4*j4+2]=v.z; av[4*j4+3]=v.w;
      }
#pragma unroll
      for (int i = 0; i < 16; i++) As[alc + i][alr] = av[i];
    }
    {
      const float* wp = W + (size_t)(k0 + blr) * D + n0;
#pragma unroll
      for (int j4 = 0; j4 < 4; j4++) {
        int n = blc + 4 * j4;
        float4 v;
        if (n0 + n < D) v = *reinterpret_cast<const float4*>(wp + n);
        else            v = make_float4(0.f, 0.f, 0.f, 0.f);
        *reinterpret_cast<float4*>(&Bs[blr][n]) = v;
      }
    }
    __syncthreads();
#pragma unroll
    for (int kk = 0; kk < 32; kk++) {
      float a[8], b[8];
      float4 t0 = *reinterpret_cast<const float4*>(&As[kk][ty * 8]);
      float4 t1 = *reinterpret_cast<const float4*>(&As[kk][ty * 8 + 4]);
      a[0]=t0.x; a[1]=t0.y; a[2]=t0.z; a[3]=t0.w; a[4]=t1.x; a[5]=t1.y; a[6]=t1.z; a[7]=t1.w;
      float4 u0 = *reinterpret_cast<const float4*>(&Bs[kk][tx * 8]);
      float4 u1 = *reinterpret_cast<const float4*>(&Bs[kk][tx * 8 + 4]);
      b[0]=u0.x; b[1]=u0.y; b[2]=u0.z; b[3]=u0.w; b[4]=u1.x; b[5]=u1.y; b[6]=u1.z; b[7]=u1.w;
#pragma unroll
      for (int i = 0; i < 8; i++)
#pragma unroll
        for (int j = 0; j < 8; j++) acc[i][j] = fmaf(a[i], b[j], acc[i][j]);
    }
    __syncthreads();
  }

#pragma unroll
  for (int i = 0; i < 8; i++) {
    int gm = m0 + ty * 8 + i;
    if (gm >= N) continue;
#pragma unroll
    for (int j4 = 0; j4 < 2; j4++) {
      int gn = n0 + tx * 8 + 4 * j4;
      if (gn < D) {
        float4 bv = *reinterpret_cast<const float4*>(bout + gn);
        float4 yv = make_float4(fmaxf(acc[i][4*j4+0] + bv.x, 0.f),
                                fmaxf(acc[i][4*j4+1] + bv.y, 0.f),
                                fmaxf(acc[i][4*j4+2] + bv.z, 0.f),
                                fmaxf(acc[i][4*j4+3] + bv.w, 0.f));
        *reinterpret_cast<float4*>(Y + (size_t)gm * D + gn) = yv;
      }
    }
  }
}

// ================= pooling (sorted protein_batch) =================

__global__ void k_pool(const float* __restrict__ X3, const float* __restrict__ feat,
                       const int* __restrict__ pb, double* __restrict__ psum,
                       int N, int D3, int F) {
  const int c = threadIdx.x;
  const int C = D3 + F;
  int i0 = blockIdx.x * 64;
  if (i0 >= N) return;
  int iend = i0 + 64; if (iend > N) iend = N;
  double acc = 0.0;
  int cur = pb[i0];
  for (int i = i0; i < iend; i++) {
    int b = pb[i];
    if (b != cur) {
      atomicAdd(&psum[(size_t)cur * C + c], acc);
      acc = 0.0; cur = b;
    }
    float v;
    if (c < D3) v = X3[(size_t)i * D3 + c];
    else        v = feat[(size_t)i * F + (c - D3)];
    acc += (double)v;
  }
  atomicAdd(&psum[(size_t)cur * C + c], acc);
}

__global__ void k_count(const int* __restrict__ pb, float* __restrict__ cnt, int N) {
  int tchunk = blockIdx.x * blockDim.x + threadIdx.x;
  int i0 = tchunk * 64;
  if (i0 >= N) return;
  int iend = i0 + 64; if (iend > N) iend = N;
  float cacc = 0.f; int cur = pb[i0];
  for (int i = i0; i < iend; i++) {
    int b = pb[i];
    if (b != cur) { atomicAdd(&cnt[cur], cacc); cacc = 0.f; cur = b; }
    cacc += 1.f;
  }
  atomicAdd(&cnt[cur], cacc);
}

// ================= FC head =================

__global__ __launch_bounds__(256)
void k_fc1(const double* __restrict__ psum, const float* __restrict__ cnt,
           const float* __restrict__ Wf1, const float* __restrict__ bf1,
           float* __restrict__ hidden, int C, int Hh) {
  int b = blockIdx.x;
  int t = threadIdx.x;
  __shared__ float gcs[512];
  float invc = 1.f / fmaxf(cnt[b], 1.f);
  for (int c = t; c < C; c += blockDim.x)
    gcs[c] = (float)psum[(size_t)b * C + c] * invc;
  __syncthreads();
  for (int j = t; j < Hh; j += blockDim.x) {
    double s = 0.0;
    for (int c = 0; c < C; c++) s += (double)gcs[c] * (double)Wf1[(size_t)c * Hh + j];
    float r = (float)s + bf1[j];
    hidden[(size_t)b * Hh + j] = fmaxf(r, 0.f);
  }
}

__global__ void k_fc2(const float* __restrict__ hidden, const float* __restrict__ Wf2,
                      const float* __restrict__ bf2, float* __restrict__ out, int Hh) {
  int b = blockIdx.x;
  int lane = threadIdx.x;  // 64
  double s = 0.0;
  for (int j = lane; j < Hh; j += 64) s += (double)hidden[(size_t)b * Hh + j] * (double)Wf2[j];
#pragma unroll
  for (int off = 32; off > 0; off >>= 1) s += __shfl_down(s, off);
  if (lane == 0) out[b] = (float)s + bf2[0];
}

// ================= launch =================

extern "C" void kernel_launch(void* const* d_in, const int* in_sizes, int n_in,
                              void* d_out, int out_size, void* d_ws, size_t ws_size,
                              hipStream_t stream) {
  const float* feature = (const float*)d_in[0];
  const int*   eidx    = (const int*)  d_in[1];
  const float* weight  = (const float*)d_in[2];
  const int*   pb      = (const int*)  d_in[3];
  const float* W1  = (const float*)d_in[4];
  const float* b1  = (const float*)d_in[5];
  const float* W2  = (const float*)d_in[6];
  const float* b2  = (const float*)d_in[7];
  const float* W3  = (const float*)d_in[8];
  const float* b3  = (const float*)d_in[9];
  const float* Wf1 = (const float*)d_in[10];
  const float* bf1 = (const float*)d_in[11];
  const float* Wf2 = (const float*)d_in[12];
  const float* bf2 = (const float*)d_in[13];

  const int F  = in_sizes[5];          // 64
  const int D2 = in_sizes[7];          // 128
  const int D3 = in_sizes[9];          // 256
  const int Hh = in_sizes[11];         // 1024
  const int N  = in_sizes[0] / F;      // 100000
  const int E  = in_sizes[1] / 2;      // 1200000
  const int B  = out_size;             // 256
  const int C  = D3 + F;               // 320

  const int* srcp = eidx;
  const int* dstp = eidx + E;
  const int nscan = (N + 1023) / 1024;

  auto al = [](size_t x) { return (x + 255) & ~(size_t)255; };
  size_t off = 0;
  auto alloc = [&](size_t bytes) { size_t o = off; off += al(bytes); return o; };
  size_t o_deg   = alloc((size_t)N * 4);
  size_t o_dinv  = alloc((size_t)N * 4);
  size_t o_sn    = alloc((size_t)N * 4);
  size_t o_cnt   = alloc((size_t)N * 4);
  size_t o_rs    = alloc((size_t)N * 4);
  size_t o_fill  = alloc((size_t)N * 4);
  size_t o_bsum  = alloc((size_t)nscan * 4);
  size_t o_epack = alloc((size_t)E * 8);
  size_t o_agg   = alloc((size_t)N * D2 * 4);     // widest aggregation input = 128
  size_t o_x1    = alloc((size_t)N * F  * 4);
  size_t o_x2    = alloc((size_t)N * D2 * 4);
  size_t o_x3    = alloc((size_t)N * D3 * 4);
  size_t o_psum  = alloc((size_t)B * C * 8);
  size_t o_gcnt  = alloc((size_t)B * 4);
  size_t o_hid   = alloc((size_t)B * Hh * 4);
  if (off > ws_size) {
    fprintf(stderr, "kernel_launch: workspace too small: need %zu, have %zu\n", off, ws_size);
    return;
  }

  char* ws = (char*)d_ws;
  float*  deg   = (float*)(ws + o_deg);
  float*  dinv  = (float*)(ws + o_dinv);
  float*  sn    = (float*)(ws + o_sn);
  int*    cntn  = (int*)  (ws + o_cnt);
  int*    rs    = (int*)  (ws + o_rs);
  int*    fill  = (int*)  (ws + o_fill);
  int*    bsum  = (int*)  (ws + o_bsum);
  int2*   epack = (int2*) (ws + o_epack);
  float*  aggb  = (float*)(ws + o_agg);
  float*  x1    = (float*)(ws + o_x1);
  float*  x2    = (float*)(ws + o_x2);
  float*  x3    = (float*)(ws + o_x3);
  double* psum  = (double*)(ws + o_psum);
  float*  gcnt  = (float*)(ws + o_gcnt);
  float*  hid   = (float*)(ws + o_hid);
  float*  out   = (float*)d_out;

  // ---- pre-pass + CSR build ----
  k_init      <<<(N + 255) / 256, 256, 0, stream>>>(deg, cntn, fill, N);
  k_edge_count<<<(E + 255) / 256, 256, 0, stream>>>(dstp, weight, deg, cntn, E);
  k_dinv      <<<(N + 255) / 256, 256, 0, stream>>>(deg, dinv, sn, N);
  k_scan1     <<<nscan, 256, 0, stream>>>(cntn, rs, bsum, N);
  k_scan2     <<<1, 64, 0, stream>>>(bsum, nscan);
  k_scan3     <<<(N + 255) / 256, 256, 0, stream>>>(rs, bsum, N);
  k_csr_fill  <<<(E + 255) / 256, 256, 0, stream>>>(srcp, dstp, weight, dinv, rs, fill, epack, E);
  k_zero_pool <<<(B * C + 255) / 256, 256, 0, stream>>>(psum, gcnt, B, C);

  // ---- layer 1: agg(feature)[N,64] @ W1[64,64] ----
  {
    int tot = N * (F / 4);
    k_aggregate<4><<<(tot + 255) / 256, 256, 0, stream>>>(feature, rs, cntn, epack, sn, aggb, N);
    dim3 g((F + 127) / 128, (N + 127) / 128);
    k_gemm_bre<<<g, 256, 0, stream>>>(aggb, W1, b1, x1, N, F, F);
  }
  // ---- layer 2: agg(x1)[N,64] @ W2[64,128] ----
  {
    int tot = N * (F / 4);
    k_aggregate<4><<<(tot + 255) / 256, 256, 0, stream>>>(x1, rs, cntn, epack, sn, aggb, N);
    dim3 g((D2 + 127) / 128, (N + 127) / 128);
    k_gemm_bre<<<g, 256, 0, stream>>>(aggb, W2, b2, x2, N, F, D2);
  }
  // ---- layer 3: agg(x2)[N,128] @ W3[128,256] ----
  {
    int tot = N * (D2 / 4);
    k_aggregate<5><<<(tot + 255) / 256, 256, 0, stream>>>(x2, rs, cntn, epack, sn, aggb, N);
    dim3 g((D3 + 127) / 128, (N + 127) / 128);
    k_gemm_bre<<<g, 256, 0, stream>>>(aggb, W3, b3, x3, N, D2, D3);
  }

  // ---- pooling + head ----
  k_count<<<((N + 63) / 64 + 255) / 256, 256, 0, stream>>>(pb, gcnt, N);
  k_pool <<<(N + 63) / 64, C, 0, stream>>>(x3, feature, pb, psum, N, D3, F);
  k_fc1  <<<B, 256, 0, stream>>>(psum, gcnt, Wf1, bf1, hid, C, Hh);
  k_fc2  <<<B, 64, 0, stream>>>(hid, Wf2, bf2, out, Hh);
}

// Round 3
// 779.384 us; speedup vs baseline: 9.8132x; 1.1527x over previous
//
#include <hip/hip_runtime.h>
#include <cstdio>
#include <cstdint>

// ================= pre-pass: degree, norms, CSR build =================

__global__ void k_init(float* __restrict__ deg, int* __restrict__ cnt,
                       int* __restrict__ fill, int N) {
  int i = blockIdx.x * blockDim.x + threadIdx.x;
  if (i < N) { deg[i] = 1.0f; cnt[i] = 0; fill[i] = 0; }  // deg starts at self-loop weight
}

__global__ void k_edge_count(const int* __restrict__ dst, const float* __restrict__ ew,
                             float* __restrict__ deg, int* __restrict__ cnt, int E) {
  int e = blockIdx.x * blockDim.x + threadIdx.x;
  if (e < E) {
    int d = dst[e];
    atomicAdd(&deg[d], ew[e]);
    atomicAdd(&cnt[d], 1);
  }
}

__global__ void k_dinv(const float* __restrict__ deg, float* __restrict__ dinv,
                       float* __restrict__ selfnorm, int N) {
  int i = blockIdx.x * blockDim.x + threadIdx.x;
  if (i < N) {
    float d = deg[i];
    float r = (d > 0.f) ? (float)(1.0 / sqrt((double)d)) : 0.f;
    dinv[i] = r;
    selfnorm[i] = r * r;
  }
}

// exclusive scan of cnt[N] -> rs[N]; 1024 elems / block (256 thr x 4)
__global__ __launch_bounds__(256)
void k_scan1(const int* __restrict__ cnt, int* __restrict__ rs,
             int* __restrict__ bsum, int N) {
  __shared__ int sh[256];
  const int t = threadIdx.x;
  const int base = blockIdx.x * 1024;
  int v[4]; int s = 0;
#pragma unroll
  for (int j = 0; j < 4; j++) {
    int idx = base + t * 4 + j;
    v[j] = (idx < N) ? cnt[idx] : 0;
    s += v[j];
  }
  sh[t] = s;
  __syncthreads();
  for (int off = 1; off < 256; off <<= 1) {
    int x = (t >= off) ? sh[t - off] : 0;
    __syncthreads();
    sh[t] += x;
    __syncthreads();
  }
  int run = sh[t] - s;  // exclusive prefix of this thread's chunk
#pragma unroll
  for (int j = 0; j < 4; j++) {
    int idx = base + t * 4 + j;
    if (idx < N) rs[idx] = run;
    run += v[j];
  }
  if (t == 255) bsum[blockIdx.x] = sh[255];
}

__global__ void k_scan2(int* __restrict__ bsum, int nb) {
  if (blockIdx.x == 0 && threadIdx.x == 0) {
    int run = 0;
    for (int i = 0; i < nb; i++) { int v = bsum[i]; bsum[i] = run; run += v; }
  }
}

__global__ void k_scan3(int* __restrict__ rs, const int* __restrict__ bsum, int N) {
  int i = blockIdx.x * blockDim.x + threadIdx.x;
  if (i < N) rs[i] += bsum[i >> 10];
}

// place each edge into its dst row: epack[pos] = {src, norm}
__global__ void k_csr_fill(const int* __restrict__ src, const int* __restrict__ dst,
                           const float* __restrict__ ew, const float* __restrict__ dinv,
                           const int* __restrict__ rs, int* __restrict__ fill,
                           int2* __restrict__ epack, int E) {
  int e = blockIdx.x * blockDim.x + threadIdx.x;
  if (e >= E) return;
  int d = dst[e], s = src[e];
  int pos = rs[d] + atomicAdd(&fill[d], 1);
  float w = dinv[s] * ew[e] * dinv[d];
  epack[pos] = make_int2(s, __float_as_int(w));
}

__global__ void k_zero_pool(double* __restrict__ psum, float* __restrict__ cnt, int B, int C) {
  int i = blockIdx.x * blockDim.x + threadIdx.x;
  if (i < B * C) psum[i] = 0.0;
  if (i < B) cnt[i] = 0.f;
}

// ================= CSR gather aggregation: AGG = Â @ X =================

template<int LOG2D4>
__global__ __launch_bounds__(256)
void k_aggregate(const float* __restrict__ X, const int* __restrict__ rs,
                 const int* __restrict__ cntn, const int2* __restrict__ epack,
                 const float* __restrict__ sn, float* __restrict__ AGG, int N) {
  const int t = blockIdx.x * blockDim.x + threadIdx.x;
  const int row = t >> LOG2D4;
  if (row >= N) return;
  const int D4 = 1 << LOG2D4;
  const int D = D4 << 2;
  const int c = (t & (D4 - 1)) << 2;

  float4 acc = *reinterpret_cast<const float4*>(X + (size_t)row * D + c);
  float s = sn[row];
  acc.x *= s; acc.y *= s; acc.z *= s; acc.w *= s;

  const int p0 = rs[row];
  const int k = cntn[row];
  for (int i = 0; i < k; i++) {
    int2 e = epack[p0 + i];
    float w = __int_as_float(e.y);
    const float4 v = *reinterpret_cast<const float4*>(X + (size_t)e.x * D + c);
    acc.x = fmaf(v.x, w, acc.x);
    acc.y = fmaf(v.y, w, acc.y);
    acc.z = fmaf(v.z, w, acc.z);
    acc.w = fmaf(v.w, w, acc.w);
  }
  *reinterpret_cast<float4*>(AGG + (size_t)row * D + c) = acc;
}

// ================= GEMM: Y = relu(X @ W + b) =================
// 128x128 tile, BK=32, 256 threads, 8x8 microtile.

__global__ __launch_bounds__(256)
void k_gemm_bre(const float* __restrict__ X, const float* __restrict__ W,
                const float* __restrict__ bout, float* __restrict__ Y,
                int N, int K, int D) {
  __shared__ float As[32][132];
  __shared__ float Bs[32][132];
  const int t  = threadIdx.x;
  const int m0 = blockIdx.y * 128;
  const int n0 = blockIdx.x * 128;
  const int ty = t >> 4, tx = t & 15;

  float acc[8][8];
#pragma unroll
  for (int i = 0; i < 8; i++)
#pragma unroll
    for (int j = 0; j < 8; j++) acc[i][j] = 0.f;

  const int alr = t >> 1, alc = (t & 1) << 4;
  const int blr = t >> 3, blc = (t & 7) << 4;
  int gra = m0 + alr; if (gra >= N) gra = N - 1;

  for (int k0 = 0; k0 < K; k0 += 32) {
    {
      const float* ap = X + (size_t)gra * K + (k0 + alc);
      float av[16];
#pragma unroll
      for (int j4 = 0; j4 < 4; j4++) {
        float4 v = *reinterpret_cast<const float4*>(ap + 4 * j4);
        av[4*j4+0]=v.x; av[4*j4+1]=v.y; av[4*j4+2]=v.z; av[4*j4+3]=v.w;
      }
#pragma unroll
      for (int i = 0; i < 16; i++) As[alc + i][alr] = av[i];
    }
    {
      const float* wp = W + (size_t)(k0 + blr) * D + n0;
#pragma unroll
      for (int j4 = 0; j4 < 4; j4++) {
        int n = blc + 4 * j4;
        float4 v;
        if (n0 + n < D) v = *reinterpret_cast<const float4*>(wp + n);
        else            v = make_float4(0.f, 0.f, 0.f, 0.f);
        *reinterpret_cast<float4*>(&Bs[blr][n]) = v;
      }
    }
    __syncthreads();
#pragma unroll
    for (int kk = 0; kk < 32; kk++) {
      float a[8], b[8];
      float4 t0 = *reinterpret_cast<const float4*>(&As[kk][ty * 8]);
      float4 t1 = *reinterpret_cast<const float4*>(&As[kk][ty * 8 + 4]);
      a[0]=t0.x; a[1]=t0.y; a[2]=t0.z; a[3]=t0.w; a[4]=t1.x; a[5]=t1.y; a[6]=t1.z; a[7]=t1.w;
      float4 u0 = *reinterpret_cast<const float4*>(&Bs[kk][tx * 8]);
      float4 u1 = *reinterpret_cast<const float4*>(&Bs[kk][tx * 8 + 4]);
      b[0]=u0.x; b[1]=u0.y; b[2]=u0.z; b[3]=u0.w; b[4]=u1.x; b[5]=u1.y; b[6]=u1.z; b[7]=u1.w;
#pragma unroll
      for (int i = 0; i < 8; i++)
#pragma unroll
        for (int j = 0; j < 8; j++) acc[i][j] = fmaf(a[i], b[j], acc[i][j]);
    }
    __syncthreads();
  }

#pragma unroll
  for (int i = 0; i < 8; i++) {
    int gm = m0 + ty * 8 + i;
    if (gm >= N) continue;
#pragma unroll
    for (int j4 = 0; j4 < 2; j4++) {
      int gn = n0 + tx * 8 + 4 * j4;
      if (gn < D) {
        float4 bv = *reinterpret_cast<const float4*>(bout + gn);
        float4 yv = make_float4(fmaxf(acc[i][4*j4+0] + bv.x, 0.f),
                                fmaxf(acc[i][4*j4+1] + bv.y, 0.f),
                                fmaxf(acc[i][4*j4+2] + bv.z, 0.f),
                                fmaxf(acc[i][4*j4+3] + bv.w, 0.f));
        *reinterpret_cast<float4*>(Y + (size_t)gm * D + gn) = yv;
      }
    }
  }
}

// ================= pooling (sorted protein_batch) =================

__global__ void k_pool(const float* __restrict__ X3, const float* __restrict__ feat,
                       const int* __restrict__ pb, double* __restrict__ psum,
                       int N, int D3, int F) {
  const int c = threadIdx.x;
  const int C = D3 + F;
  int i0 = blockIdx.x * 64;
  if (i0 >= N) return;
  int iend = i0 + 64; if (iend > N) iend = N;
  double acc = 0.0;
  int cur = pb[i0];
  for (int i = i0; i < iend; i++) {
    int b = pb[i];
    if (b != cur) {
      atomicAdd(&psum[(size_t)cur * C + c], acc);
      acc = 0.0; cur = b;
    }
    float v;
    if (c < D3) v = X3[(size_t)i * D3 + c];
    else        v = feat[(size_t)i * F + (c - D3)];
    acc += (double)v;
  }
  atomicAdd(&psum[(size_t)cur * C + c], acc);
}

__global__ void k_count(const int* __restrict__ pb, float* __restrict__ cnt, int N) {
  int tchunk = blockIdx.x * blockDim.x + threadIdx.x;
  int i0 = tchunk * 64;
  if (i0 >= N) return;
  int iend = i0 + 64; if (iend > N) iend = N;
  float cacc = 0.f; int cur = pb[i0];
  for (int i = i0; i < iend; i++) {
    int b = pb[i];
    if (b != cur) { atomicAdd(&cnt[cur], cacc); cacc = 0.f; cur = b; }
    cacc += 1.f;
  }
  atomicAdd(&cnt[cur], cacc);
}

// ================= FC head =================

// normalize pooled sums -> fp32 gc [B, C]
__global__ void k_gc(const double* __restrict__ psum, const float* __restrict__ cnt,
                     float* __restrict__ gc, int B, int C) {
  int i = blockIdx.x * blockDim.x + threadIdx.x;
  if (i < B * C) {
    int b = i / C;
    gc[i] = (float)psum[i] * (1.f / fmaxf(cnt[b], 1.f));
  }
}

// hidden[b][j] = relu(dot(gc[b,:], Wf1[:,j]) + bf1[j]); one thread per (b,j),
// 4 independent partial accumulators to break the FMA dependency chain.
__global__ __launch_bounds__(256)
void k_fc1(const float* __restrict__ gc, const float* __restrict__ Wf1,
           const float* __restrict__ bf1, float* __restrict__ hidden,
           int C, int Hh) {
  const int b = blockIdx.y;
  const int j = blockIdx.x * 256 + threadIdx.x;
  if (j >= Hh) return;
  const float* g = gc + (size_t)b * C;
  const float* w = Wf1 + j;
  float a0 = 0.f, a1 = 0.f, a2 = 0.f, a3 = 0.f;
  int c = 0;
  for (; c + 4 <= C; c += 4) {
    a0 = fmaf(g[c + 0], w[(size_t)(c + 0) * Hh], a0);
    a1 = fmaf(g[c + 1], w[(size_t)(c + 1) * Hh], a1);
    a2 = fmaf(g[c + 2], w[(size_t)(c + 2) * Hh], a2);
    a3 = fmaf(g[c + 3], w[(size_t)(c + 3) * Hh], a3);
  }
  for (; c < C; c++) a0 = fmaf(g[c], w[(size_t)c * Hh], a0);
  float r = ((a0 + a1) + (a2 + a3)) + bf1[j];
  hidden[(size_t)b * Hh + j] = fmaxf(r, 0.f);
}

__global__ void k_fc2(const float* __restrict__ hidden, const float* __restrict__ Wf2,
                      const float* __restrict__ bf2, float* __restrict__ out, int Hh) {
  int b = blockIdx.x;
  int lane = threadIdx.x;  // 64
  double s = 0.0;
  for (int j = lane; j < Hh; j += 64) s += (double)hidden[(size_t)b * Hh + j] * (double)Wf2[j];
#pragma unroll
  for (int off = 32; off > 0; off >>= 1) s += __shfl_down(s, off);
  if (lane == 0) out[b] = (float)s + bf2[0];
}

// ================= launch =================

extern "C" void kernel_launch(void* const* d_in, const int* in_sizes, int n_in,
                              void* d_out, int out_size, void* d_ws, size_t ws_size,
                              hipStream_t stream) {
  const float* feature = (const float*)d_in[0];
  const int*   eidx    = (const int*)  d_in[1];
  const float* weight  = (const float*)d_in[2];
  const int*   pb      = (const int*)  d_in[3];
  const float* W1  = (const float*)d_in[4];
  const float* b1  = (const float*)d_in[5];
  const float* W2  = (const float*)d_in[6];
  const float* b2  = (const float*)d_in[7];
  const float* W3  = (const float*)d_in[8];
  const float* b3  = (const float*)d_in[9];
  const float* Wf1 = (const float*)d_in[10];
  const float* bf1 = (const float*)d_in[11];
  const float* Wf2 = (const float*)d_in[12];
  const float* bf2 = (const float*)d_in[13];

  const int F  = in_sizes[5];          // 64
  const int D2 = in_sizes[7];          // 128
  const int D3 = in_sizes[9];          // 256
  const int Hh = in_sizes[11];         // 1024
  const int N  = in_sizes[0] / F;      // 100000
  const int E  = in_sizes[1] / 2;      // 1200000
  const int B  = out_size;             // 256
  const int C  = D3 + F;               // 320

  const int* srcp = eidx;
  const int* dstp = eidx + E;
  const int nscan = (N + 1023) / 1024;

  auto al = [](size_t x) { return (x + 255) & ~(size_t)255; };
  size_t off = 0;
  auto alloc = [&](size_t bytes) { size_t o = off; off += al(bytes); return o; };
  size_t o_deg   = alloc((size_t)N * 4);
  size_t o_dinv  = alloc((size_t)N * 4);
  size_t o_sn    = alloc((size_t)N * 4);
  size_t o_cnt   = alloc((size_t)N * 4);
  size_t o_rs    = alloc((size_t)N * 4);
  size_t o_fill  = alloc((size_t)N * 4);
  size_t o_bsum  = alloc((size_t)nscan * 4);
  size_t o_epack = alloc((size_t)E * 8);
  size_t o_agg   = alloc((size_t)N * D2 * 4);     // widest aggregation input = 128
  size_t o_x1    = alloc((size_t)N * F  * 4);
  size_t o_x2    = alloc((size_t)N * D2 * 4);
  size_t o_x3    = alloc((size_t)N * D3 * 4);
  size_t o_psum  = alloc((size_t)B * C * 8);
  size_t o_gc    = alloc((size_t)B * C * 4);
  size_t o_gcnt  = alloc((size_t)B * 4);
  size_t o_hid   = alloc((size_t)B * Hh * 4);
  if (off > ws_size) {
    fprintf(stderr, "kernel_launch: workspace too small: need %zu, have %zu\n", off, ws_size);
    return;
  }

  char* ws = (char*)d_ws;
  float*  deg   = (float*)(ws + o_deg);
  float*  dinv  = (float*)(ws + o_dinv);
  float*  sn    = (float*)(ws + o_sn);
  int*    cntn  = (int*)  (ws + o_cnt);
  int*    rs    = (int*)  (ws + o_rs);
  int*    fill  = (int*)  (ws + o_fill);
  int*    bsum  = (int*)  (ws + o_bsum);
  int2*   epack = (int2*) (ws + o_epack);
  float*  aggb  = (float*)(ws + o_agg);
  float*  x1    = (float*)(ws + o_x1);
  float*  x2    = (float*)(ws + o_x2);
  float*  x3    = (float*)(ws + o_x3);
  double* psum  = (double*)(ws + o_psum);
  float*  gcbuf = (float*)(ws + o_gc);
  float*  gcnt  = (float*)(ws + o_gcnt);
  float*  hid   = (float*)(ws + o_hid);
  float*  out   = (float*)d_out;

  // ---- pre-pass + CSR build ----
  k_init      <<<(N + 255) / 256, 256, 0, stream>>>(deg, cntn, fill, N);
  k_edge_count<<<(E + 255) / 256, 256, 0, stream>>>(dstp, weight, deg, cntn, E);
  k_dinv      <<<(N + 255) / 256, 256, 0, stream>>>(deg, dinv, sn, N);
  k_scan1     <<<nscan, 256, 0, stream>>>(cntn, rs, bsum, N);
  k_scan2     <<<1, 64, 0, stream>>>(bsum, nscan);
  k_scan3     <<<(N + 255) / 256, 256, 0, stream>>>(rs, bsum, N);
  k_csr_fill  <<<(E + 255) / 256, 256, 0, stream>>>(srcp, dstp, weight, dinv, rs, fill, epack, E);
  k_zero_pool <<<(B * C + 255) / 256, 256, 0, stream>>>(psum, gcnt, B, C);

  // ---- layer 1: agg(feature)[N,64] @ W1[64,64] ----
  {
    int tot = N * (F / 4);
    k_aggregate<4><<<(tot + 255) / 256, 256, 0, stream>>>(feature, rs, cntn, epack, sn, aggb, N);
    dim3 g((F + 127) / 128, (N + 127) / 128);
    k_gemm_bre<<<g, 256, 0, stream>>>(aggb, W1, b1, x1, N, F, F);
  }
  // ---- layer 2: agg(x1)[N,64] @ W2[64,128] ----
  {
    int tot = N * (F / 4);
    k_aggregate<4><<<(tot + 255) / 256, 256, 0, stream>>>(x1, rs, cntn, epack, sn, aggb, N);
    dim3 g((D2 + 127) / 128, (N + 127) / 128);
    k_gemm_bre<<<g, 256, 0, stream>>>(aggb, W2, b2, x2, N, F, D2);
  }
  // ---- layer 3: agg(x2)[N,128] @ W3[128,256] ----
  {
    int tot = N * (D2 / 4);
    k_aggregate<5><<<(tot + 255) / 256, 256, 0, stream>>>(x2, rs, cntn, epack, sn, aggb, N);
    dim3 g((D3 + 127) / 128, (N + 127) / 128);
    k_gemm_bre<<<g, 256, 0, stream>>>(aggb, W3, b3, x3, N, D2, D3);
  }

  // ---- pooling + head ----
  k_count<<<((N + 63) / 64 + 255) / 256, 256, 0, stream>>>(pb, gcnt, N);
  k_pool <<<(N + 63) / 64, C, 0, stream>>>(x3, feature, pb, psum, N, D3, F);
  k_gc   <<<(B * C + 255) / 256, 256, 0, stream>>>(psum, gcnt, gcbuf, B, C);
  {
    dim3 g((Hh + 255) / 256, B);
    k_fc1<<<g, 256, 0, stream>>>(gcbuf, Wf1, bf1, hid, C, Hh);
  }
  k_fc2  <<<B, 64, 0, stream>>>(hid, Wf2, bf2, out, Hh);
}

// Round 4
// 714.040 us; speedup vs baseline: 10.7112x; 1.0915x over previous
//
#include <hip/hip_runtime.h>
#include <cstdio>
#include <cstdint>

typedef short bf16x8 __attribute__((ext_vector_type(8)));
typedef float f32x4 __attribute__((ext_vector_type(4)));

__device__ inline unsigned short f2bf(float f) {  // fp32 -> bf16 RNE
  unsigned u = __float_as_uint(f);
  u += 0x7fffu + ((u >> 16) & 1u);
  return (unsigned short)(u >> 16);
}
__device__ inline float bf2f(unsigned short h) {
  return __uint_as_float(((unsigned)h) << 16);
}

// ================= pre-pass: degree, norms, CSR build =================

__global__ void k_init(float* __restrict__ deg, int* __restrict__ cnt,
                       int* __restrict__ fill, int N) {
  int i = blockIdx.x * blockDim.x + threadIdx.x;
  if (i < N) { deg[i] = 1.0f; cnt[i] = 0; fill[i] = 0; }
}

__global__ void k_edge_count(const int* __restrict__ dst, const float* __restrict__ ew,
                             float* __restrict__ deg, int* __restrict__ cnt, int E) {
  int e = blockIdx.x * blockDim.x + threadIdx.x;
  if (e < E) {
    int d = dst[e];
    atomicAdd(&deg[d], ew[e]);
    atomicAdd(&cnt[d], 1);
  }
}

__global__ void k_dinv(const float* __restrict__ deg, float* __restrict__ dinv,
                       float* __restrict__ selfnorm, int N) {
  int i = blockIdx.x * blockDim.x + threadIdx.x;
  if (i < N) {
    float d = deg[i];
    float r = (d > 0.f) ? (float)(1.0 / sqrt((double)d)) : 0.f;
    dinv[i] = r;
    selfnorm[i] = r * r;
  }
}

__global__ __launch_bounds__(256)
void k_scan1(const int* __restrict__ cnt, int* __restrict__ rs,
             int* __restrict__ bsum, int N) {
  __shared__ int sh[256];
  const int t = threadIdx.x;
  const int base = blockIdx.x * 1024;
  int v[4]; int s = 0;
#pragma unroll
  for (int j = 0; j < 4; j++) {
    int idx = base + t * 4 + j;
    v[j] = (idx < N) ? cnt[idx] : 0;
    s += v[j];
  }
  sh[t] = s;
  __syncthreads();
  for (int off = 1; off < 256; off <<= 1) {
    int x = (t >= off) ? sh[t - off] : 0;
    __syncthreads();
    sh[t] += x;
    __syncthreads();
  }
  int run = sh[t] - s;
#pragma unroll
  for (int j = 0; j < 4; j++) {
    int idx = base + t * 4 + j;
    if (idx < N) rs[idx] = run;
    run += v[j];
  }
  if (t == 255) bsum[blockIdx.x] = sh[255];
}

__global__ void k_scan2(int* __restrict__ bsum, int nb) {
  if (blockIdx.x == 0 && threadIdx.x == 0) {
    int run = 0;
    for (int i = 0; i < nb; i++) { int v = bsum[i]; bsum[i] = run; run += v; }
  }
}

__global__ void k_scan3(int* __restrict__ rs, const int* __restrict__ bsum, int N) {
  int i = blockIdx.x * blockDim.x + threadIdx.x;
  if (i < N) rs[i] += bsum[i >> 10];
}

__global__ void k_csr_fill(const int* __restrict__ src, const int* __restrict__ dst,
                           const float* __restrict__ ew, const float* __restrict__ dinv,
                           const int* __restrict__ rs, int* __restrict__ fill,
                           int2* __restrict__ epack, int E) {
  int e = blockIdx.x * blockDim.x + threadIdx.x;
  if (e >= E) return;
  int d = dst[e], s = src[e];
  int pos = rs[d] + atomicAdd(&fill[d], 1);
  float w = dinv[s] * ew[e] * dinv[d];
  epack[pos] = make_int2(s, __float_as_int(w));
}

__global__ void k_zero_pool(double* __restrict__ psum, float* __restrict__ cnt, int B, int C) {
  int i = blockIdx.x * blockDim.x + threadIdx.x;
  if (i < B * C) psum[i] = 0.0;
  if (i < B) cnt[i] = 0.f;
}

// split W [K][D] fp32 -> transposed bf16 hi/lo [D][K]
__global__ void k_wsplit(const float* __restrict__ W, ushort* __restrict__ Th,
                         ushort* __restrict__ Tl, int K, int D) {
  int i = blockIdx.x * blockDim.x + threadIdx.x;
  if (i >= K * D) return;
  int k = i / D, n = i - k * D;
  float f = W[i];
  ushort h = f2bf(f);
  Th[(size_t)n * K + k] = h;
  Tl[(size_t)n * K + k] = f2bf(f - bf2f(h));
}

// ================= CSR gather aggregation: AGG = Â @ X (bf16 hi/lo out) ==

template<int LOG2D4>
__global__ __launch_bounds__(256)
void k_aggregate(const float* __restrict__ X, const int* __restrict__ rs,
                 const int* __restrict__ cntn, const int2* __restrict__ epack,
                 const float* __restrict__ sn, ushort* __restrict__ AH,
                 ushort* __restrict__ AL, int N) {
  const int t = blockIdx.x * blockDim.x + threadIdx.x;
  const int row = t >> LOG2D4;
  if (row >= N) return;
  const int D4 = 1 << LOG2D4;
  const int D = D4 << 2;
  const int c = (t & (D4 - 1)) << 2;

  float4 acc = *reinterpret_cast<const float4*>(X + (size_t)row * D + c);
  float s = sn[row];
  acc.x *= s; acc.y *= s; acc.z *= s; acc.w *= s;

  const int p0 = rs[row];
  const int k = cntn[row];
  for (int i = 0; i < k; i++) {
    int2 e = epack[p0 + i];
    float w = __int_as_float(e.y);
    const float4 v = *reinterpret_cast<const float4*>(X + (size_t)e.x * D + c);
    acc.x = fmaf(v.x, w, acc.x);
    acc.y = fmaf(v.y, w, acc.y);
    acc.z = fmaf(v.z, w, acc.z);
    acc.w = fmaf(v.w, w, acc.w);
  }
  ushort4 h, l;
  h.x = f2bf(acc.x); l.x = f2bf(acc.x - bf2f(h.x));
  h.y = f2bf(acc.y); l.y = f2bf(acc.y - bf2f(h.y));
  h.z = f2bf(acc.z); l.z = f2bf(acc.z - bf2f(h.z));
  h.w = f2bf(acc.w); l.w = f2bf(acc.w - bf2f(h.w));
  *reinterpret_cast<ushort4*>(AH + (size_t)row * D + c) = h;
  *reinterpret_cast<ushort4*>(AL + (size_t)row * D + c) = l;
}

// ================= split-bf16 MFMA GEMM: Y = relu(A @ W + b) =================
// A given as bf16 hi/lo [N][KT]; W as transposed bf16 hi/lo [D][KT].
// acc += ah*bh + ah*bl + al*bh  (error ~2^-16 relative).
// M_TILE=128, N_TILE=NT, BK=64; 256 threads = 4 waves, each wave 32 rows.

template<int KT, int NT>
__global__ __launch_bounds__(256)
void k_gemm_mfma(const ushort* __restrict__ Ah, const ushort* __restrict__ Al,
                 const ushort* __restrict__ Bh, const ushort* __restrict__ Bl,
                 const float* __restrict__ bias, float* __restrict__ Y,
                 int N, int D) {
  constexpr int PK = 72;  // padded row length (bf16) -> <=2-way LDS aliasing
  __shared__ __align__(16) ushort sAh[128 * PK];
  __shared__ __align__(16) ushort sAl[128 * PK];
  __shared__ __align__(16) ushort sBh[NT * PK];
  __shared__ __align__(16) ushort sBl[NT * PK];
  const int t = threadIdx.x;
  const int wave = t >> 6, lane = t & 63;
  const int quad = lane >> 4, l16 = lane & 15;
  const int m0 = blockIdx.y * 128;
  const int n0 = blockIdx.x * NT;

  f32x4 acc[2][NT / 16];
#pragma unroll
  for (int mi = 0; mi < 2; mi++)
#pragma unroll
    for (int ni = 0; ni < NT / 16; ni++) acc[mi][ni] = (f32x4){0.f, 0.f, 0.f, 0.f};

  for (int k0 = 0; k0 < KT; k0 += 64) {
    if (k0) __syncthreads();
    // stage A tiles: 128 rows x 64 k = 1024 chunks of 16B (8 bf16) each
#pragma unroll
    for (int it = 0; it < 4; it++) {
      int c = t + 256 * it;
      int row = c >> 3, kc = (c & 7) << 3;
      int gr = m0 + row; if (gr >= N) gr = N - 1;
      size_t gofs = (size_t)gr * KT + k0 + kc;
      *reinterpret_cast<int4*>(&sAh[row * PK + kc]) = *reinterpret_cast<const int4*>(Ah + gofs);
      *reinterpret_cast<int4*>(&sAl[row * PK + kc]) = *reinterpret_cast<const int4*>(Al + gofs);
    }
    // stage B tiles: NT rows x 64 k
#pragma unroll
    for (int it = 0; it < NT / 32; it++) {
      int c = t + 256 * it;
      int row = c >> 3, kc = (c & 7) << 3;
      size_t gofs = (size_t)(n0 + row) * KT + k0 + kc;
      *reinterpret_cast<int4*>(&sBh[row * PK + kc]) = *reinterpret_cast<const int4*>(Bh + gofs);
      *reinterpret_cast<int4*>(&sBl[row * PK + kc]) = *reinterpret_cast<const int4*>(Bl + gofs);
    }
    __syncthreads();
#pragma unroll
    for (int ks = 0; ks < 2; ks++) {
      const int kk = ks * 32 + quad * 8;
      bf16x8 aH[2], aL[2];
#pragma unroll
      for (int mi = 0; mi < 2; mi++) {
        int r = wave * 32 + mi * 16 + l16;
        aH[mi] = *reinterpret_cast<const bf16x8*>(&sAh[r * PK + kk]);
        aL[mi] = *reinterpret_cast<const bf16x8*>(&sAl[r * PK + kk]);
      }
#pragma unroll
      for (int ni = 0; ni < NT / 16; ni++) {
        int r = ni * 16 + l16;
        bf16x8 bH = *reinterpret_cast<const bf16x8*>(&sBh[r * PK + kk]);
        bf16x8 bL = *reinterpret_cast<const bf16x8*>(&sBl[r * PK + kk]);
#pragma unroll
        for (int mi = 0; mi < 2; mi++) {
          acc[mi][ni] = __builtin_amdgcn_mfma_f32_16x16x32_bf16(aH[mi], bH, acc[mi][ni], 0, 0, 0);
          acc[mi][ni] = __builtin_amdgcn_mfma_f32_16x16x32_bf16(aH[mi], bL, acc[mi][ni], 0, 0, 0);
          acc[mi][ni] = __builtin_amdgcn_mfma_f32_16x16x32_bf16(aL[mi], bH, acc[mi][ni], 0, 0, 0);
        }
      }
    }
  }
  // epilogue: C/D layout col=lane&15, row=quad*4+reg
#pragma unroll
  for (int mi = 0; mi < 2; mi++) {
    int rb = m0 + wave * 32 + mi * 16 + quad * 4;
#pragma unroll
    for (int ni = 0; ni < NT / 16; ni++) {
      int col = n0 + ni * 16 + l16;
      float bv = bias[col];
#pragma unroll
      for (int r = 0; r < 4; r++) {
        int row = rb + r;
        if (row < N) Y[(size_t)row * D + col] = fmaxf(acc[mi][ni][r] + bv, 0.f);
      }
    }
  }
}

// ================= pooling (sorted protein_batch) =================

__global__ void k_pool(const float* __restrict__ X3, const float* __restrict__ feat,
                       const int* __restrict__ pb, double* __restrict__ psum,
                       int N, int D3, int F) {
  const int c = threadIdx.x;
  const int C = D3 + F;
  int i0 = blockIdx.x * 64;
  if (i0 >= N) return;
  int iend = i0 + 64; if (iend > N) iend = N;
  double acc = 0.0;
  int cur = pb[i0];
  for (int i = i0; i < iend; i++) {
    int b = pb[i];
    if (b != cur) {
      atomicAdd(&psum[(size_t)cur * C + c], acc);
      acc = 0.0; cur = b;
    }
    float v;
    if (c < D3) v = X3[(size_t)i * D3 + c];
    else        v = feat[(size_t)i * F + (c - D3)];
    acc += (double)v;
  }
  atomicAdd(&psum[(size_t)cur * C + c], acc);
}

__global__ void k_count(const int* __restrict__ pb, float* __restrict__ cnt, int N) {
  int tchunk = blockIdx.x * blockDim.x + threadIdx.x;
  int i0 = tchunk * 64;
  if (i0 >= N) return;
  int iend = i0 + 64; if (iend > N) iend = N;
  float cacc = 0.f; int cur = pb[i0];
  for (int i = i0; i < iend; i++) {
    int b = pb[i];
    if (b != cur) { atomicAdd(&cnt[cur], cacc); cacc = 0.f; cur = b; }
    cacc += 1.f;
  }
  atomicAdd(&cnt[cur], cacc);
}

// ================= FC head =================

__global__ void k_gc(const double* __restrict__ psum, const float* __restrict__ cnt,
                     float* __restrict__ gc, int B, int C) {
  int i = blockIdx.x * blockDim.x + threadIdx.x;
  if (i < B * C) {
    int b = i / C;
    gc[i] = (float)psum[i] * (1.f / fmaxf(cnt[b], 1.f));
  }
}

__global__ __launch_bounds__(256)
void k_fc1(const float* __restrict__ gc, const float* __restrict__ Wf1,
           const float* __restrict__ bf1, float* __restrict__ hidden,
           int C, int Hh) {
  const int b = blockIdx.y;
  const int j = blockIdx.x * 256 + threadIdx.x;
  if (j >= Hh) return;
  const float* g = gc + (size_t)b * C;
  const float* w = Wf1 + j;
  float a0 = 0.f, a1 = 0.f, a2 = 0.f, a3 = 0.f;
  int c = 0;
  for (; c + 4 <= C; c += 4) {
    a0 = fmaf(g[c + 0], w[(size_t)(c + 0) * Hh], a0);
    a1 = fmaf(g[c + 1], w[(size_t)(c + 1) * Hh], a1);
    a2 = fmaf(g[c + 2], w[(size_t)(c + 2) * Hh], a2);
    a3 = fmaf(g[c + 3], w[(size_t)(c + 3) * Hh], a3);
  }
  for (; c < C; c++) a0 = fmaf(g[c], w[(size_t)c * Hh], a0);
  float r = ((a0 + a1) + (a2 + a3)) + bf1[j];
  hidden[(size_t)b * Hh + j] = fmaxf(r, 0.f);
}

__global__ void k_fc2(const float* __restrict__ hidden, const float* __restrict__ Wf2,
                      const float* __restrict__ bf2, float* __restrict__ out, int Hh) {
  int b = blockIdx.x;
  int lane = threadIdx.x;  // 64
  double s = 0.0;
  for (int j = lane; j < Hh; j += 64) s += (double)hidden[(size_t)b * Hh + j] * (double)Wf2[j];
#pragma unroll
  for (int off = 32; off > 0; off >>= 1) s += __shfl_down(s, off);
  if (lane == 0) out[b] = (float)s + bf2[0];
}

// ================= launch =================

extern "C" void kernel_launch(void* const* d_in, const int* in_sizes, int n_in,
                              void* d_out, int out_size, void* d_ws, size_t ws_size,
                              hipStream_t stream) {
  const float* feature = (const float*)d_in[0];
  const int*   eidx    = (const int*)  d_in[1];
  const float* weight  = (const float*)d_in[2];
  const int*   pb      = (const int*)  d_in[3];
  const float* W1  = (const float*)d_in[4];
  const float* b1  = (const float*)d_in[5];
  const float* W2  = (const float*)d_in[6];
  const float* b2  = (const float*)d_in[7];
  const float* W3  = (const float*)d_in[8];
  const float* b3  = (const float*)d_in[9];
  const float* Wf1 = (const float*)d_in[10];
  const float* bf1 = (const float*)d_in[11];
  const float* Wf2 = (const float*)d_in[12];
  const float* bf2 = (const float*)d_in[13];

  const int F  = in_sizes[5];          // 64
  const int D2 = in_sizes[7];          // 128
  const int D3 = in_sizes[9];          // 256
  const int Hh = in_sizes[11];         // 1024
  const int N  = in_sizes[0] / F;      // 100000
  const int E  = in_sizes[1] / 2;      // 1200000
  const int B  = out_size;             // 256
  const int C  = D3 + F;               // 320

  const int* srcp = eidx;
  const int* dstp = eidx + E;
  const int nscan = (N + 1023) / 1024;

  auto al = [](size_t x) { return (x + 255) & ~(size_t)255; };
  size_t off = 0;
  auto alloc = [&](size_t bytes) { size_t o = off; off += al(bytes); return o; };
  size_t o_deg   = alloc((size_t)N * 4);
  size_t o_dinv  = alloc((size_t)N * 4);
  size_t o_sn    = alloc((size_t)N * 4);
  size_t o_cnt   = alloc((size_t)N * 4);
  size_t o_rs    = alloc((size_t)N * 4);
  size_t o_fill  = alloc((size_t)N * 4);
  size_t o_bsum  = alloc((size_t)nscan * 4);
  size_t o_epack = alloc((size_t)E * 8);
  size_t o_aggh  = alloc((size_t)N * D2 * 2);   // bf16 hi (max K = 128)
  size_t o_aggl  = alloc((size_t)N * D2 * 2);   // bf16 lo
  size_t o_x1    = alloc((size_t)N * F  * 4);
  size_t o_x2    = alloc((size_t)N * D2 * 4);
  size_t o_x3    = alloc((size_t)N * D3 * 4);
  size_t o_w1h   = alloc((size_t)F  * F  * 2);
  size_t o_w1l   = alloc((size_t)F  * F  * 2);
  size_t o_w2h   = alloc((size_t)F  * D2 * 2);
  size_t o_w2l   = alloc((size_t)F  * D2 * 2);
  size_t o_w3h   = alloc((size_t)D2 * D3 * 2);
  size_t o_w3l   = alloc((size_t)D2 * D3 * 2);
  size_t o_psum  = alloc((size_t)B * C * 8);
  size_t o_gc    = alloc((size_t)B * C * 4);
  size_t o_gcnt  = alloc((size_t)B * 4);
  size_t o_hid   = alloc((size_t)B * Hh * 4);
  if (off > ws_size) {
    fprintf(stderr, "kernel_launch: workspace too small: need %zu, have %zu\n", off, ws_size);
    return;
  }

  char* ws = (char*)d_ws;
  float*  deg   = (float*)(ws + o_deg);
  float*  dinv  = (float*)(ws + o_dinv);
  float*  sn    = (float*)(ws + o_sn);
  int*    cntn  = (int*)  (ws + o_cnt);
  int*    rs    = (int*)  (ws + o_rs);
  int*    fill  = (int*)  (ws + o_fill);
  int*    bsum  = (int*)  (ws + o_bsum);
  int2*   epack = (int2*) (ws + o_epack);
  ushort* aggh  = (ushort*)(ws + o_aggh);
  ushort* aggl  = (ushort*)(ws + o_aggl);
  float*  x1    = (float*)(ws + o_x1);
  float*  x2    = (float*)(ws + o_x2);
  float*  x3    = (float*)(ws + o_x3);
  ushort* w1h   = (ushort*)(ws + o_w1h);
  ushort* w1l   = (ushort*)(ws + o_w1l);
  ushort* w2h   = (ushort*)(ws + o_w2h);
  ushort* w2l   = (ushort*)(ws + o_w2l);
  ushort* w3h   = (ushort*)(ws + o_w3h);
  ushort* w3l   = (ushort*)(ws + o_w3l);
  double* psum  = (double*)(ws + o_psum);
  float*  gcbuf = (float*)(ws + o_gc);
  float*  gcnt  = (float*)(ws + o_gcnt);
  float*  hid   = (float*)(ws + o_hid);
  float*  out   = (float*)d_out;

  // ---- pre-pass + CSR build + weight split ----
  k_init      <<<(N + 255) / 256, 256, 0, stream>>>(deg, cntn, fill, N);
  k_edge_count<<<(E + 255) / 256, 256, 0, stream>>>(dstp, weight, deg, cntn, E);
  k_dinv      <<<(N + 255) / 256, 256, 0, stream>>>(deg, dinv, sn, N);
  k_scan1     <<<nscan, 256, 0, stream>>>(cntn, rs, bsum, N);
  k_scan2     <<<1, 64, 0, stream>>>(bsum, nscan);
  k_scan3     <<<(N + 255) / 256, 256, 0, stream>>>(rs, bsum, N);
  k_csr_fill  <<<(E + 255) / 256, 256, 0, stream>>>(srcp, dstp, weight, dinv, rs, fill, epack, E);
  k_zero_pool <<<(B * C + 255) / 256, 256, 0, stream>>>(psum, gcnt, B, C);
  k_wsplit    <<<(F  * F  + 255) / 256, 256, 0, stream>>>(W1, w1h, w1l, F,  F);
  k_wsplit    <<<(F  * D2 + 255) / 256, 256, 0, stream>>>(W2, w2h, w2l, F,  D2);
  k_wsplit    <<<(D2 * D3 + 255) / 256, 256, 0, stream>>>(W3, w3h, w3l, D2, D3);

  const int gy = (N + 127) / 128;

  // ---- layer 1: agg(feature)[N,64] @ W1[64,64] ----
  {
    int tot = N * (F / 4);
    k_aggregate<4><<<(tot + 255) / 256, 256, 0, stream>>>(feature, rs, cntn, epack, sn, aggh, aggl, N);
    dim3 g(1, gy);
    k_gemm_mfma<64, 64><<<g, 256, 0, stream>>>(aggh, aggl, w1h, w1l, b1, x1, N, F);
  }
  // ---- layer 2: agg(x1)[N,64] @ W2[64,128] ----
  {
    int tot = N * (F / 4);
    k_aggregate<4><<<(tot + 255) / 256, 256, 0, stream>>>(x1, rs, cntn, epack, sn, aggh, aggl, N);
    dim3 g(1, gy);
    k_gemm_mfma<64, 128><<<g, 256, 0, stream>>>(aggh, aggl, w2h, w2l, b2, x2, N, D2);
  }
  // ---- layer 3: agg(x2)[N,128] @ W3[128,256] ----
  {
    int tot = N * (D2 / 4);
    k_aggregate<5><<<(tot + 255) / 256, 256, 0, stream>>>(x2, rs, cntn, epack, sn, aggh, aggl, N);
    dim3 g(2, gy);
    k_gemm_mfma<128, 128><<<g, 256, 0, stream>>>(aggh, aggl, w3h, w3l, b3, x3, N, D3);
  }

  // ---- pooling + head ----
  k_count<<<((N + 63) / 64 + 255) / 256, 256, 0, stream>>>(pb, gcnt, N);
  k_pool <<<(N + 63) / 64, C, 0, stream>>>(x3, feature, pb, psum, N, D3, F);
  k_gc   <<<(B * C + 255) / 256, 256, 0, stream>>>(psum, gcnt, gcbuf, B, C);
  {
    dim3 g((Hh + 255) / 256, B);
    k_fc1<<<g, 256, 0, stream>>>(gcbuf, Wf1, bf1, hid, C, Hh);
  }
  k_fc2  <<<B, 64, 0, stream>>>(hid, Wf2, bf2, out, Hh);
}

// Round 5
// 659.911 us; speedup vs baseline: 11.5898x; 1.0820x over previous
//
#include <hip/hip_runtime.h>
#include <cstdio>
#include <cstdint>

typedef short bf16x8 __attribute__((ext_vector_type(8)));
typedef float f32x4 __attribute__((ext_vector_type(4)));

__device__ inline unsigned short f2bf(float f) {  // fp32 -> bf16 RNE
  unsigned u = __float_as_uint(f);
  u += 0x7fffu + ((u >> 16) & 1u);
  return (unsigned short)(u >> 16);
}
__device__ inline float bf2f(unsigned short h) {
  return __uint_as_float(((unsigned)h) << 16);
}

// ================= pre-pass: degree, norms, CSR build =================
// packed[d]: high 24 bits = in-edge count, low 40 bits = sum(ew) in 2^-30
// fixed point (capacity 1024.0; quant error ~1e-9 relative on deg).

__global__ void k_init(unsigned long long* __restrict__ packed,
                       int* __restrict__ fill, int N) {
  int i = blockIdx.x * blockDim.x + threadIdx.x;
  if (i < N) { packed[i] = 0ull; fill[i] = 0; }
}

__global__ void k_count_pack(const int* __restrict__ dst, const float* __restrict__ ew,
                             unsigned long long* __restrict__ packed, int E) {
  int e = blockIdx.x * blockDim.x + threadIdx.x;
  if (e < E) {
    unsigned long long q = (unsigned long long)(ew[e] * 1073741824.0f + 0.5f);
    atomicAdd(&packed[dst[e]], (1ull << 40) | q);
  }
}

__global__ void k_dinv(const unsigned long long* __restrict__ packed,
                       float* __restrict__ dinv, float* __restrict__ selfnorm, int N) {
  int i = blockIdx.x * blockDim.x + threadIdx.x;
  if (i < N) {
    unsigned long long p = packed[i];
    double deg = 1.0 + (double)(p & 0xFFFFFFFFFFull) * (1.0 / 1073741824.0);
    float r = (float)(1.0 / sqrt(deg));   // deg >= 1 always (self-loop)
    dinv[i] = r;
    selfnorm[i] = r * r;
  }
}

// exclusive scan of cnt (= packed>>40) -> rs[N]; 1024 elems / block
__global__ __launch_bounds__(256)
void k_scan1(const unsigned long long* __restrict__ packed, int* __restrict__ rs,
             int* __restrict__ bsum, int N) {
  __shared__ int sh[256];
  const int t = threadIdx.x;
  const int base = blockIdx.x * 1024;
  int v[4]; int s = 0;
#pragma unroll
  for (int j = 0; j < 4; j++) {
    int idx = base + t * 4 + j;
    v[j] = (idx < N) ? (int)(packed[idx] >> 40) : 0;
    s += v[j];
  }
  sh[t] = s;
  __syncthreads();
  for (int off = 1; off < 256; off <<= 1) {
    int x = (t >= off) ? sh[t - off] : 0;
    __syncthreads();
    sh[t] += x;
    __syncthreads();
  }
  int run = sh[t] - s;
#pragma unroll
  for (int j = 0; j < 4; j++) {
    int idx = base + t * 4 + j;
    if (idx < N) rs[idx] = run;
    run += v[j];
  }
  if (t == 255) bsum[blockIdx.x] = sh[255];
}

__global__ void k_scan2(int* __restrict__ bsum, int nb) {
  if (blockIdx.x == 0 && threadIdx.x == 0) {
    int run = 0;
    for (int i = 0; i < nb; i++) { int v = bsum[i]; bsum[i] = run; run += v; }
  }
}

__global__ void k_scan3(int* __restrict__ rs, const int* __restrict__ bsum, int N) {
  int i = blockIdx.x * blockDim.x + threadIdx.x;
  if (i < N) rs[i] += bsum[i >> 10];
}

__global__ void k_csr_fill(const int* __restrict__ src, const int* __restrict__ dst,
                           const float* __restrict__ ew, const float* __restrict__ dinv,
                           const int* __restrict__ rs, int* __restrict__ fill,
                           int2* __restrict__ epack, int E) {
  int e = blockIdx.x * blockDim.x + threadIdx.x;
  if (e >= E) return;
  int d = dst[e], s = src[e];
  int pos = rs[d] + atomicAdd(&fill[d], 1);
  float w = dinv[s] * ew[e] * dinv[d];
  epack[pos] = make_int2(s, __float_as_int(w));
}

__global__ void k_zero_pool(double* __restrict__ psum, float* __restrict__ cnt, int B, int C) {
  int i = blockIdx.x * blockDim.x + threadIdx.x;
  if (i < B * C) psum[i] = 0.0;
  if (i < B) cnt[i] = 0.f;
}

// split W [K][D] fp32 -> transposed bf16 hi/lo [D][K]
__global__ void k_wsplit(const float* __restrict__ W, ushort* __restrict__ Th,
                         ushort* __restrict__ Tl, int K, int D) {
  int i = blockIdx.x * blockDim.x + threadIdx.x;
  if (i >= K * D) return;
  int k = i / D, n = i - k * D;
  float f = W[i];
  ushort h = f2bf(f);
  Th[(size_t)n * K + k] = h;
  Tl[(size_t)n * K + k] = f2bf(f - bf2f(h));
}

// ================= CSR gather aggregation: AGG = Â @ X (bf16 hi/lo out) ==

template<int LOG2D4>
__global__ __launch_bounds__(256)
void k_aggregate(const float* __restrict__ X, const int* __restrict__ rs,
                 const int* __restrict__ cnt_rs_end, const int2* __restrict__ epack,
                 const float* __restrict__ sn, ushort* __restrict__ AH,
                 ushort* __restrict__ AL, int N) {
  const int t = blockIdx.x * blockDim.x + threadIdx.x;
  const int row = t >> LOG2D4;
  if (row >= N) return;
  const int D4 = 1 << LOG2D4;
  const int D = D4 << 2;
  const int c = (t & (D4 - 1)) << 2;

  float4 acc = *reinterpret_cast<const float4*>(X + (size_t)row * D + c);
  float s = sn[row];
  acc.x *= s; acc.y *= s; acc.z *= s; acc.w *= s;

  const int p0 = rs[row];
  const int pe = cnt_rs_end[row];
  for (int i = p0; i < pe; i++) {
    int2 e = epack[i];
    float w = __int_as_float(e.y);
    const float4 v = *reinterpret_cast<const float4*>(X + (size_t)e.x * D + c);
    acc.x = fmaf(v.x, w, acc.x);
    acc.y = fmaf(v.y, w, acc.y);
    acc.z = fmaf(v.z, w, acc.z);
    acc.w = fmaf(v.w, w, acc.w);
  }
  ushort4 h, l;
  h.x = f2bf(acc.x); l.x = f2bf(acc.x - bf2f(h.x));
  h.y = f2bf(acc.y); l.y = f2bf(acc.y - bf2f(h.y));
  h.z = f2bf(acc.z); l.z = f2bf(acc.z - bf2f(h.z));
  h.w = f2bf(acc.w); l.w = f2bf(acc.w - bf2f(h.w));
  *reinterpret_cast<ushort4*>(AH + (size_t)row * D + c) = h;
  *reinterpret_cast<ushort4*>(AL + (size_t)row * D + c) = l;
}

// after fill, fill[d] == cnt[d]; rs_end[row] = rs[row] + fill[row]
__global__ void k_rs_end(const int* __restrict__ rs, const int* __restrict__ fill,
                         int* __restrict__ rse, int N) {
  int i = blockIdx.x * blockDim.x + threadIdx.x;
  if (i < N) rse[i] = rs[i] + fill[i];
}

// ================= split-bf16 MFMA GEMM: Y = relu(A @ W + b) =================

template<int KT, int NT>
__global__ __launch_bounds__(256)
void k_gemm_mfma(const ushort* __restrict__ Ah, const ushort* __restrict__ Al,
                 const ushort* __restrict__ Bh, const ushort* __restrict__ Bl,
                 const float* __restrict__ bias, float* __restrict__ Y,
                 int N, int D) {
  constexpr int PK = 72;  // padded row length (bf16) -> <=2-way LDS aliasing
  __shared__ __align__(16) ushort sAh[128 * PK];
  __shared__ __align__(16) ushort sAl[128 * PK];
  __shared__ __align__(16) ushort sBh[NT * PK];
  __shared__ __align__(16) ushort sBl[NT * PK];
  const int t = threadIdx.x;
  const int wave = t >> 6, lane = t & 63;
  const int quad = lane >> 4, l16 = lane & 15;
  const int m0 = blockIdx.y * 128;
  const int n0 = blockIdx.x * NT;

  f32x4 acc[2][NT / 16];
#pragma unroll
  for (int mi = 0; mi < 2; mi++)
#pragma unroll
    for (int ni = 0; ni < NT / 16; ni++) acc[mi][ni] = (f32x4){0.f, 0.f, 0.f, 0.f};

  for (int k0 = 0; k0 < KT; k0 += 64) {
    if (k0) __syncthreads();
#pragma unroll
    for (int it = 0; it < 4; it++) {
      int c = t + 256 * it;
      int row = c >> 3, kc = (c & 7) << 3;
      int gr = m0 + row; if (gr >= N) gr = N - 1;
      size_t gofs = (size_t)gr * KT + k0 + kc;
      *reinterpret_cast<int4*>(&sAh[row * PK + kc]) = *reinterpret_cast<const int4*>(Ah + gofs);
      *reinterpret_cast<int4*>(&sAl[row * PK + kc]) = *reinterpret_cast<const int4*>(Al + gofs);
    }
#pragma unroll
    for (int it = 0; it < NT / 32; it++) {
      int c = t + 256 * it;
      int row = c >> 3, kc = (c & 7) << 3;
      size_t gofs = (size_t)(n0 + row) * KT + k0 + kc;
      *reinterpret_cast<int4*>(&sBh[row * PK + kc]) = *reinterpret_cast<const int4*>(Bh + gofs);
      *reinterpret_cast<int4*>(&sBl[row * PK + kc]) = *reinterpret_cast<const int4*>(Bl + gofs);
    }
    __syncthreads();
#pragma unroll
    for (int ks = 0; ks < 2; ks++) {
      const int kk = ks * 32 + quad * 8;
      bf16x8 aH[2], aL[2];
#pragma unroll
      for (int mi = 0; mi < 2; mi++) {
        int r = wave * 32 + mi * 16 + l16;
        aH[mi] = *reinterpret_cast<const bf16x8*>(&sAh[r * PK + kk]);
        aL[mi] = *reinterpret_cast<const bf16x8*>(&sAl[r * PK + kk]);
      }
#pragma unroll
      for (int ni = 0; ni < NT / 16; ni++) {
        int r = ni * 16 + l16;
        bf16x8 bH = *reinterpret_cast<const bf16x8*>(&sBh[r * PK + kk]);
        bf16x8 bL = *reinterpret_cast<const bf16x8*>(&sBl[r * PK + kk]);
#pragma unroll
        for (int mi = 0; mi < 2; mi++) {
          acc[mi][ni] = __builtin_amdgcn_mfma_f32_16x16x32_bf16(aH[mi], bH, acc[mi][ni], 0, 0, 0);
          acc[mi][ni] = __builtin_amdgcn_mfma_f32_16x16x32_bf16(aH[mi], bL, acc[mi][ni], 0, 0, 0);
          acc[mi][ni] = __builtin_amdgcn_mfma_f32_16x16x32_bf16(aL[mi], bH, acc[mi][ni], 0, 0, 0);
        }
      }
    }
  }
  // epilogue: C/D layout col=lane&15, row=quad*4+reg
#pragma unroll
  for (int mi = 0; mi < 2; mi++) {
    int rb = m0 + wave * 32 + mi * 16 + quad * 4;
#pragma unroll
    for (int ni = 0; ni < NT / 16; ni++) {
      int col = n0 + ni * 16 + l16;
      float bv = bias[col];
#pragma unroll
      for (int r = 0; r < 4; r++) {
        int row = rb + r;
        if (row < N) Y[(size_t)row * D + col] = fmaxf(acc[mi][ni][r] + bv, 0.f);
      }
    }
  }
}

// ================= pooling (sorted protein_batch) =================

__global__ void k_pool(const float* __restrict__ X3, const float* __restrict__ feat,
                       const int* __restrict__ pb, double* __restrict__ psum,
                       int N, int D3, int F) {
  const int c = threadIdx.x;
  const int C = D3 + F;
  int i0 = blockIdx.x * 64;
  if (i0 >= N) return;
  int iend = i0 + 64; if (iend > N) iend = N;
  double acc = 0.0;
  int cur = pb[i0];
  for (int i = i0; i < iend; i++) {
    int b = pb[i];
    if (b != cur) {
      atomicAdd(&psum[(size_t)cur * C + c], acc);
      acc = 0.0; cur = b;
    }
    float v;
    if (c < D3) v = X3[(size_t)i * D3 + c];
    else        v = feat[(size_t)i * F + (c - D3)];
    acc += (double)v;
  }
  atomicAdd(&psum[(size_t)cur * C + c], acc);
}

__global__ void k_count(const int* __restrict__ pb, float* __restrict__ cnt, int N) {
  int tchunk = blockIdx.x * blockDim.x + threadIdx.x;
  int i0 = tchunk * 64;
  if (i0 >= N) return;
  int iend = i0 + 64; if (iend > N) iend = N;
  float cacc = 0.f; int cur = pb[i0];
  for (int i = i0; i < iend; i++) {
    int b = pb[i];
    if (b != cur) { atomicAdd(&cnt[cur], cacc); cacc = 0.f; cur = b; }
    cacc += 1.f;
  }
  atomicAdd(&cnt[cur], cacc);
}

// ================= FC head =================

__global__ void k_gc(const double* __restrict__ psum, const float* __restrict__ cnt,
                     float* __restrict__ gc, int B, int C) {
  int i = blockIdx.x * blockDim.x + threadIdx.x;
  if (i < B * C) {
    int b = i / C;
    gc[i] = (float)psum[i] * (1.f / fmaxf(cnt[b], 1.f));
  }
}

__global__ __launch_bounds__(256)
void k_fc1(const float* __restrict__ gc, const float* __restrict__ Wf1,
           const float* __restrict__ bf1, float* __restrict__ hidden,
           int C, int Hh) {
  const int b = blockIdx.y;
  const int j = blockIdx.x * 256 + threadIdx.x;
  if (j >= Hh) return;
  const float* g = gc + (size_t)b * C;
  const float* w = Wf1 + j;
  float a0 = 0.f, a1 = 0.f, a2 = 0.f, a3 = 0.f;
  int c = 0;
  for (; c + 4 <= C; c += 4) {
    a0 = fmaf(g[c + 0], w[(size_t)(c + 0) * Hh], a0);
    a1 = fmaf(g[c + 1], w[(size_t)(c + 1) * Hh], a1);
    a2 = fmaf(g[c + 2], w[(size_t)(c + 2) * Hh], a2);
    a3 = fmaf(g[c + 3], w[(size_t)(c + 3) * Hh], a3);
  }
  for (; c < C; c++) a0 = fmaf(g[c], w[(size_t)c * Hh], a0);
  float r = ((a0 + a1) + (a2 + a3)) + bf1[j];
  hidden[(size_t)b * Hh + j] = fmaxf(r, 0.f);
}

__global__ void k_fc2(const float* __restrict__ hidden, const float* __restrict__ Wf2,
                      const float* __restrict__ bf2, float* __restrict__ out, int Hh) {
  int b = blockIdx.x;
  int lane = threadIdx.x;  // 64
  double s = 0.0;
  for (int j = lane; j < Hh; j += 64) s += (double)hidden[(size_t)b * Hh + j] * (double)Wf2[j];
#pragma unroll
  for (int off = 32; off > 0; off >>= 1) s += __shfl_down(s, off);
  if (lane == 0) out[b] = (float)s + bf2[0];
}

// ================= launch =================

extern "C" void kernel_launch(void* const* d_in, const int* in_sizes, int n_in,
                              void* d_out, int out_size, void* d_ws, size_t ws_size,
                              hipStream_t stream) {
  const float* feature = (const float*)d_in[0];
  const int*   eidx    = (const int*)  d_in[1];
  const float* weight  = (const float*)d_in[2];
  const int*   pb      = (const int*)  d_in[3];
  const float* W1  = (const float*)d_in[4];
  const float* b1  = (const float*)d_in[5];
  const float* W2  = (const float*)d_in[6];
  const float* b2  = (const float*)d_in[7];
  const float* W3  = (const float*)d_in[8];
  const float* b3  = (const float*)d_in[9];
  const float* Wf1 = (const float*)d_in[10];
  const float* bf1 = (const float*)d_in[11];
  const float* Wf2 = (const float*)d_in[12];
  const float* bf2 = (const float*)d_in[13];

  const int F  = in_sizes[5];          // 64
  const int D2 = in_sizes[7];          // 128
  const int D3 = in_sizes[9];          // 256
  const int Hh = in_sizes[11];         // 1024
  const int N  = in_sizes[0] / F;      // 100000
  const int E  = in_sizes[1] / 2;      // 1200000
  const int B  = out_size;             // 256
  const int C  = D3 + F;               // 320

  const int* srcp = eidx;
  const int* dstp = eidx + E;
  const int nscan = (N + 1023) / 1024;

  auto al = [](size_t x) { return (x + 255) & ~(size_t)255; };
  size_t off = 0;
  auto alloc = [&](size_t bytes) { size_t o = off; off += al(bytes); return o; };
  size_t o_pack  = alloc((size_t)N * 8);
  size_t o_dinv  = alloc((size_t)N * 4);
  size_t o_sn    = alloc((size_t)N * 4);
  size_t o_rs    = alloc((size_t)N * 4);
  size_t o_rse   = alloc((size_t)N * 4);
  size_t o_fill  = alloc((size_t)N * 4);
  size_t o_bsum  = alloc((size_t)nscan * 4);
  size_t o_epack = alloc((size_t)E * 8);
  size_t o_aggh  = alloc((size_t)N * D2 * 2);   // bf16 hi (max K = 128)
  size_t o_aggl  = alloc((size_t)N * D2 * 2);   // bf16 lo
  size_t o_x1    = alloc((size_t)N * F  * 4);
  size_t o_x2    = alloc((size_t)N * D2 * 4);
  size_t o_x3    = alloc((size_t)N * D3 * 4);
  size_t o_w1h   = alloc((size_t)F  * F  * 2);
  size_t o_w1l   = alloc((size_t)F  * F  * 2);
  size_t o_w2h   = alloc((size_t)F  * D2 * 2);
  size_t o_w2l   = alloc((size_t)F  * D2 * 2);
  size_t o_w3h   = alloc((size_t)D2 * D3 * 2);
  size_t o_w3l   = alloc((size_t)D2 * D3 * 2);
  size_t o_psum  = alloc((size_t)B * C * 8);
  size_t o_gc    = alloc((size_t)B * C * 4);
  size_t o_gcnt  = alloc((size_t)B * 4);
  size_t o_hid   = alloc((size_t)B * Hh * 4);
  if (off > ws_size) {
    fprintf(stderr, "kernel_launch: workspace too small: need %zu, have %zu\n", off, ws_size);
    return;
  }

  char* ws = (char*)d_ws;
  unsigned long long* packed = (unsigned long long*)(ws + o_pack);
  float*  dinv  = (float*)(ws + o_dinv);
  float*  sn    = (float*)(ws + o_sn);
  int*    rs    = (int*)  (ws + o_rs);
  int*    rse   = (int*)  (ws + o_rse);
  int*    fill  = (int*)  (ws + o_fill);
  int*    bsum  = (int*)  (ws + o_bsum);
  int2*   epack = (int2*) (ws + o_epack);
  ushort* aggh  = (ushort*)(ws + o_aggh);
  ushort* aggl  = (ushort*)(ws + o_aggl);
  float*  x1    = (float*)(ws + o_x1);
  float*  x2    = (float*)(ws + o_x2);
  float*  x3    = (float*)(ws + o_x3);
  ushort* w1h   = (ushort*)(ws + o_w1h);
  ushort* w1l   = (ushort*)(ws + o_w1l);
  ushort* w2h   = (ushort*)(ws + o_w2h);
  ushort* w2l   = (ushort*)(ws + o_w2l);
  ushort* w3h   = (ushort*)(ws + o_w3h);
  ushort* w3l   = (ushort*)(ws + o_w3l);
  double* psum  = (double*)(ws + o_psum);
  float*  gcbuf = (float*)(ws + o_gc);
  float*  gcnt  = (float*)(ws + o_gcnt);
  float*  hid   = (float*)(ws + o_hid);
  float*  out   = (float*)d_out;

  // ---- pre-pass + CSR build + weight split ----
  k_init       <<<(N + 255) / 256, 256, 0, stream>>>(packed, fill, N);
  k_count_pack <<<(E + 255) / 256, 256, 0, stream>>>(dstp, weight, packed, E);
  k_dinv       <<<(N + 255) / 256, 256, 0, stream>>>(packed, dinv, sn, N);
  k_scan1      <<<nscan, 256, 0, stream>>>(packed, rs, bsum, N);
  k_scan2      <<<1, 64, 0, stream>>>(bsum, nscan);
  k_scan3      <<<(N + 255) / 256, 256, 0, stream>>>(rs, bsum, N);
  k_csr_fill   <<<(E + 255) / 256, 256, 0, stream>>>(srcp, dstp, weight, dinv, rs, fill, epack, E);
  k_rs_end     <<<(N + 255) / 256, 256, 0, stream>>>(rs, fill, rse, N);
  k_zero_pool  <<<(B * C + 255) / 256, 256, 0, stream>>>(psum, gcnt, B, C);
  k_wsplit     <<<(F  * F  + 255) / 256, 256, 0, stream>>>(W1, w1h, w1l, F,  F);
  k_wsplit     <<<(F  * D2 + 255) / 256, 256, 0, stream>>>(W2, w2h, w2l, F,  D2);
  k_wsplit     <<<(D2 * D3 + 255) / 256, 256, 0, stream>>>(W3, w3h, w3l, D2, D3);

  const int gy = (N + 127) / 128;

  // ---- layer 1: agg(feature)[N,64] @ W1[64,64] ----
  {
    int tot = N * (F / 4);
    k_aggregate<4><<<(tot + 255) / 256, 256, 0, stream>>>(feature, rs, rse, epack, sn, aggh, aggl, N);
    dim3 g(1, gy);
    k_gemm_mfma<64, 64><<<g, 256, 0, stream>>>(aggh, aggl, w1h, w1l, b1, x1, N, F);
  }
  // ---- layer 2: agg(x1)[N,64] @ W2[64,128] ----
  {
    int tot = N * (F / 4);
    k_aggregate<4><<<(tot + 255) / 256, 256, 0, stream>>>(x1, rs, rse, epack, sn, aggh, aggl, N);
    dim3 g(1, gy);
    k_gemm_mfma<64, 128><<<g, 256, 0, stream>>>(aggh, aggl, w2h, w2l, b2, x2, N, D2);
  }
  // ---- layer 3: agg(x2)[N,128] @ W3[128,256] ----
  {
    int tot = N * (D2 / 4);
    k_aggregate<5><<<(tot + 255) / 256, 256, 0, stream>>>(x2, rs, rse, epack, sn, aggh, aggl, N);
    dim3 g(2, gy);
    k_gemm_mfma<128, 128><<<g, 256, 0, stream>>>(aggh, aggl, w3h, w3l, b3, x3, N, D3);
  }

  // ---- pooling + head ----
  k_count<<<((N + 63) / 64 + 255) / 256, 256, 0, stream>>>(pb, gcnt, N);
  k_pool <<<(N + 63) / 64, C, 0, stream>>>(x3, feature, pb, psum, N, D3, F);
  k_gc   <<<(B * C + 255) / 256, 256, 0, stream>>>(psum, gcnt, gcbuf, B, C);
  {
    dim3 g((Hh + 255) / 256, B);
    k_fc1<<<g, 256, 0, stream>>>(gcbuf, Wf1, bf1, hid, C, Hh);
  }
  k_fc2  <<<B, 64, 0, stream>>>(hid, Wf2, bf2, out, Hh);
}

// Round 6
// 571.586 us; speedup vs baseline: 13.3807x; 1.1545x over previous
//
#include <hip/hip_runtime.h>
#include <cstdio>
#include <cstdint>

typedef short bf16x8 __attribute__((ext_vector_type(8)));
typedef float f32x4 __attribute__((ext_vector_type(4)));

__device__ inline unsigned short f2bf(float f) {  // fp32 -> bf16 RNE
  unsigned u = __float_as_uint(f);
  u += 0x7fffu + ((u >> 16) & 1u);
  return (unsigned short)(u >> 16);
}
__device__ inline float bf2f(unsigned short h) {
  return __uint_as_float(((unsigned)h) << 16);
}

// ================= pre-pass: degree, norms, CSR build =================
// packed[d]: high 24 bits = in-edge count, low 40 bits = sum(ew) in 2^-30
// fixed point (capacity 1024.0; quant error ~1e-9 relative on deg).

__global__ void k_init(unsigned long long* __restrict__ packed,
                       int* __restrict__ fill, int N) {
  int i = blockIdx.x * blockDim.x + threadIdx.x;
  if (i < N) { packed[i] = 0ull; fill[i] = 0; }
}

__global__ void k_count_pack(const int* __restrict__ dst, const float* __restrict__ ew,
                             unsigned long long* __restrict__ packed, int E) {
  int e = blockIdx.x * blockDim.x + threadIdx.x;
  if (e < E) {
    unsigned long long q = (unsigned long long)(ew[e] * 1073741824.0f + 0.5f);
    atomicAdd(&packed[dst[e]], (1ull << 40) | q);
  }
}

__global__ void k_dinv(const unsigned long long* __restrict__ packed,
                       float* __restrict__ dinv, float* __restrict__ selfnorm, int N) {
  int i = blockIdx.x * blockDim.x + threadIdx.x;
  if (i < N) {
    unsigned long long p = packed[i];
    double deg = 1.0 + (double)(p & 0xFFFFFFFFFFull) * (1.0 / 1073741824.0);
    float r = (float)(1.0 / sqrt(deg));   // deg >= 1 always (self-loop)
    dinv[i] = r;
    selfnorm[i] = r * r;
  }
}

// exclusive scan of cnt (= packed>>40) -> rs[N]; 1024 elems / block
__global__ __launch_bounds__(256)
void k_scan1(const unsigned long long* __restrict__ packed, int* __restrict__ rs,
             int* __restrict__ bsum, int N) {
  __shared__ int sh[256];
  const int t = threadIdx.x;
  const int base = blockIdx.x * 1024;
  int v[4]; int s = 0;
#pragma unroll
  for (int j = 0; j < 4; j++) {
    int idx = base + t * 4 + j;
    v[j] = (idx < N) ? (int)(packed[idx] >> 40) : 0;
    s += v[j];
  }
  sh[t] = s;
  __syncthreads();
  for (int off = 1; off < 256; off <<= 1) {
    int x = (t >= off) ? sh[t - off] : 0;
    __syncthreads();
    sh[t] += x;
    __syncthreads();
  }
  int run = sh[t] - s;
#pragma unroll
  for (int j = 0; j < 4; j++) {
    int idx = base + t * 4 + j;
    if (idx < N) rs[idx] = run;
    run += v[j];
  }
  if (t == 255) bsum[blockIdx.x] = sh[255];
}

__global__ void k_scan2(int* __restrict__ bsum, int nb) {
  if (blockIdx.x == 0 && threadIdx.x == 0) {
    int run = 0;
    for (int i = 0; i < nb; i++) { int v = bsum[i]; bsum[i] = run; run += v; }
  }
}

__global__ void k_scan3(int* __restrict__ rs, const int* __restrict__ bsum, int N) {
  int i = blockIdx.x * blockDim.x + threadIdx.x;
  if (i < N) rs[i] += bsum[i >> 10];
}

__global__ void k_csr_fill(const int* __restrict__ src, const int* __restrict__ dst,
                           const float* __restrict__ ew, const float* __restrict__ dinv,
                           const int* __restrict__ rs, int* __restrict__ fill,
                           int2* __restrict__ epack, int E) {
  int e = blockIdx.x * blockDim.x + threadIdx.x;
  if (e >= E) return;
  int d = dst[e], s = src[e];
  int pos = rs[d] + atomicAdd(&fill[d], 1);
  float w = dinv[s] * ew[e] * dinv[d];
  epack[pos] = make_int2(s, __float_as_int(w));
}

// rs_end[row] = rs[row] + fill[row]
__global__ void k_rs_end(const int* __restrict__ rs, const int* __restrict__ fill,
                         int* __restrict__ rse, int N) {
  int i = blockIdx.x * blockDim.x + threadIdx.x;
  if (i < N) rse[i] = rs[i] + fill[i];
}

__global__ void k_zero_pool(double* __restrict__ psum, float* __restrict__ cnt, int B, int C) {
  int i = blockIdx.x * blockDim.x + threadIdx.x;
  if (i < B * C) psum[i] = 0.0;
  if (i < B) cnt[i] = 0.f;
}

// split W [K][D] fp32 -> transposed bf16 hi/lo [D][K]
__global__ void k_wsplit(const float* __restrict__ W, ushort* __restrict__ Th,
                         ushort* __restrict__ Tl, int K, int D) {
  int i = blockIdx.x * blockDim.x + threadIdx.x;
  if (i >= K * D) return;
  int k = i / D, n = i - k * D;
  float f = W[i];
  ushort h = f2bf(f);
  Th[(size_t)n * K + k] = h;
  Tl[(size_t)n * K + k] = f2bf(f - bf2f(h));
}

// fp32 -> bf16 (RNE), 4 elems/thread
__global__ void k_tobf(const float* __restrict__ X, ushort* __restrict__ Y, int n) {
  int base = (blockIdx.x * blockDim.x + threadIdx.x) * 4;
  if (base < n) {
    float4 v = *reinterpret_cast<const float4*>(X + base);
    ushort4 h;
    h.x = f2bf(v.x); h.y = f2bf(v.y); h.z = f2bf(v.z); h.w = f2bf(v.w);
    *reinterpret_cast<ushort4*>(Y + base) = h;
  }
}

// ================= CSR gather aggregation (bf16 in, bf16 hi/lo out) ======
// lanes/row = D/8; each lane handles 8 cols via one 16B load per gather.

__device__ inline void bf8_fma(const int4 v, float w, float* acc) {
  acc[0] = fmaf(__uint_as_float((unsigned)v.x << 16), w, acc[0]);
  acc[1] = fmaf(__uint_as_float((unsigned)v.x & 0xffff0000u), w, acc[1]);
  acc[2] = fmaf(__uint_as_float((unsigned)v.y << 16), w, acc[2]);
  acc[3] = fmaf(__uint_as_float((unsigned)v.y & 0xffff0000u), w, acc[3]);
  acc[4] = fmaf(__uint_as_float((unsigned)v.z << 16), w, acc[4]);
  acc[5] = fmaf(__uint_as_float((unsigned)v.z & 0xffff0000u), w, acc[5]);
  acc[6] = fmaf(__uint_as_float((unsigned)v.w << 16), w, acc[6]);
  acc[7] = fmaf(__uint_as_float((unsigned)v.w & 0xffff0000u), w, acc[7]);
}

template<int LOG2L>
__global__ __launch_bounds__(256)
void k_aggregate_b(const ushort* __restrict__ Xb, const int* __restrict__ rs,
                   const int* __restrict__ rse, const int2* __restrict__ epack,
                   const float* __restrict__ sn, ushort* __restrict__ AH,
                   ushort* __restrict__ AL, int N) {
  const int t = blockIdx.x * blockDim.x + threadIdx.x;
  const int row = t >> LOG2L;
  if (row >= N) return;
  const int L = 1 << LOG2L;
  const int D = L << 3;
  const int c = (t & (L - 1)) << 3;

  float acc[8];
  {
    int4 v = *reinterpret_cast<const int4*>(Xb + (size_t)row * D + c);
    float s = sn[row];
    acc[0] = s * __uint_as_float((unsigned)v.x << 16);
    acc[1] = s * __uint_as_float((unsigned)v.x & 0xffff0000u);
    acc[2] = s * __uint_as_float((unsigned)v.y << 16);
    acc[3] = s * __uint_as_float((unsigned)v.y & 0xffff0000u);
    acc[4] = s * __uint_as_float((unsigned)v.z << 16);
    acc[5] = s * __uint_as_float((unsigned)v.z & 0xffff0000u);
    acc[6] = s * __uint_as_float((unsigned)v.w << 16);
    acc[7] = s * __uint_as_float((unsigned)v.w & 0xffff0000u);
  }
  const int p0 = rs[row], pe = rse[row];
  for (int i = p0; i < pe; i++) {
    int2 e = epack[i];
    float w = __int_as_float(e.y);
    int4 v = *reinterpret_cast<const int4*>(Xb + (size_t)e.x * D + c);
    bf8_fma(v, w, acc);
  }
  ushort h[8], l[8];
#pragma unroll
  for (int j = 0; j < 8; j++) {
    h[j] = f2bf(acc[j]);
    l[j] = f2bf(acc[j] - bf2f(h[j]));
  }
  size_t o = (size_t)row * D + c;
  *reinterpret_cast<ushort4*>(AH + o)     = make_ushort4(h[0], h[1], h[2], h[3]);
  *reinterpret_cast<ushort4*>(AH + o + 4) = make_ushort4(h[4], h[5], h[6], h[7]);
  *reinterpret_cast<ushort4*>(AL + o)     = make_ushort4(l[0], l[1], l[2], l[3]);
  *reinterpret_cast<ushort4*>(AL + o + 4) = make_ushort4(l[4], l[5], l[6], l[7]);
}

// ================= split-bf16 MFMA GEMM: Y = relu(A @ W + b) =================
// OUTBF=1: write bf16; OUTBF=0: write fp32.

template<int KT, int NT, int OUTBF>
__global__ __launch_bounds__(256)
void k_gemm_mfma(const ushort* __restrict__ Ah, const ushort* __restrict__ Al,
                 const ushort* __restrict__ Bh, const ushort* __restrict__ Bl,
                 const float* __restrict__ bias, void* __restrict__ Yv,
                 int N, int D) {
  constexpr int PK = 72;  // padded row length (bf16) -> <=2-way LDS aliasing
  __shared__ __align__(16) ushort sAh[128 * PK];
  __shared__ __align__(16) ushort sAl[128 * PK];
  __shared__ __align__(16) ushort sBh[NT * PK];
  __shared__ __align__(16) ushort sBl[NT * PK];
  const int t = threadIdx.x;
  const int wave = t >> 6, lane = t & 63;
  const int quad = lane >> 4, l16 = lane & 15;
  const int m0 = blockIdx.y * 128;
  const int n0 = blockIdx.x * NT;

  f32x4 acc[2][NT / 16];
#pragma unroll
  for (int mi = 0; mi < 2; mi++)
#pragma unroll
    for (int ni = 0; ni < NT / 16; ni++) acc[mi][ni] = (f32x4){0.f, 0.f, 0.f, 0.f};

  for (int k0 = 0; k0 < KT; k0 += 64) {
    if (k0) __syncthreads();
#pragma unroll
    for (int it = 0; it < 4; it++) {
      int c = t + 256 * it;
      int row = c >> 3, kc = (c & 7) << 3;
      int gr = m0 + row; if (gr >= N) gr = N - 1;
      size_t gofs = (size_t)gr * KT + k0 + kc;
      *reinterpret_cast<int4*>(&sAh[row * PK + kc]) = *reinterpret_cast<const int4*>(Ah + gofs);
      *reinterpret_cast<int4*>(&sAl[row * PK + kc]) = *reinterpret_cast<const int4*>(Al + gofs);
    }
#pragma unroll
    for (int it = 0; it < NT / 32; it++) {
      int c = t + 256 * it;
      int row = c >> 3, kc = (c & 7) << 3;
      size_t gofs = (size_t)(n0 + row) * KT + k0 + kc;
      *reinterpret_cast<int4*>(&sBh[row * PK + kc]) = *reinterpret_cast<const int4*>(Bh + gofs);
      *reinterpret_cast<int4*>(&sBl[row * PK + kc]) = *reinterpret_cast<const int4*>(Bl + gofs);
    }
    __syncthreads();
#pragma unroll
    for (int ks = 0; ks < 2; ks++) {
      const int kk = ks * 32 + quad * 8;
      bf16x8 aH[2], aL[2];
#pragma unroll
      for (int mi = 0; mi < 2; mi++) {
        int r = wave * 32 + mi * 16 + l16;
        aH[mi] = *reinterpret_cast<const bf16x8*>(&sAh[r * PK + kk]);
        aL[mi] = *reinterpret_cast<const bf16x8*>(&sAl[r * PK + kk]);
      }
#pragma unroll
      for (int ni = 0; ni < NT / 16; ni++) {
        int r = ni * 16 + l16;
        bf16x8 bH = *reinterpret_cast<const bf16x8*>(&sBh[r * PK + kk]);
        bf16x8 bL = *reinterpret_cast<const bf16x8*>(&sBl[r * PK + kk]);
#pragma unroll
        for (int mi = 0; mi < 2; mi++) {
          acc[mi][ni] = __builtin_amdgcn_mfma_f32_16x16x32_bf16(aH[mi], bH, acc[mi][ni], 0, 0, 0);
          acc[mi][ni] = __builtin_amdgcn_mfma_f32_16x16x32_bf16(aH[mi], bL, acc[mi][ni], 0, 0, 0);
          acc[mi][ni] = __builtin_amdgcn_mfma_f32_16x16x32_bf16(aL[mi], bH, acc[mi][ni], 0, 0, 0);
        }
      }
    }
  }
  // epilogue: C/D layout col=lane&15, row=quad*4+reg
#pragma unroll
  for (int mi = 0; mi < 2; mi++) {
    int rb = m0 + wave * 32 + mi * 16 + quad * 4;
#pragma unroll
    for (int ni = 0; ni < NT / 16; ni++) {
      int col = n0 + ni * 16 + l16;
      float bv = bias[col];
#pragma unroll
      for (int r = 0; r < 4; r++) {
        int row = rb + r;
        if (row < N) {
          float y = fmaxf(acc[mi][ni][r] + bv, 0.f);
          if (OUTBF) ((ushort*)Yv)[(size_t)row * D + col] = f2bf(y);
          else       ((float*) Yv)[(size_t)row * D + col] = y;
        }
      }
    }
  }
}

// ================= pooling (sorted protein_batch) =================

__global__ void k_pool(const ushort* __restrict__ X3b, const float* __restrict__ feat,
                       const int* __restrict__ pb, double* __restrict__ psum,
                       int N, int D3, int F) {
  const int c = threadIdx.x;
  const int C = D3 + F;
  int i0 = blockIdx.x * 64;
  if (i0 >= N) return;
  int iend = i0 + 64; if (iend > N) iend = N;
  double acc = 0.0;
  int cur = pb[i0];
  for (int i = i0; i < iend; i++) {
    int b = pb[i];
    if (b != cur) {
      atomicAdd(&psum[(size_t)cur * C + c], acc);
      acc = 0.0; cur = b;
    }
    float v;
    if (c < D3) v = bf2f(X3b[(size_t)i * D3 + c]);
    else        v = feat[(size_t)i * F + (c - D3)];
    acc += (double)v;
  }
  atomicAdd(&psum[(size_t)cur * C + c], acc);
}

__global__ void k_count(const int* __restrict__ pb, float* __restrict__ cnt, int N) {
  int tchunk = blockIdx.x * blockDim.x + threadIdx.x;
  int i0 = tchunk * 64;
  if (i0 >= N) return;
  int iend = i0 + 64; if (iend > N) iend = N;
  float cacc = 0.f; int cur = pb[i0];
  for (int i = i0; i < iend; i++) {
    int b = pb[i];
    if (b != cur) { atomicAdd(&cnt[cur], cacc); cacc = 0.f; cur = b; }
    cacc += 1.f;
  }
  atomicAdd(&cnt[cur], cacc);
}

// ================= FC head =================

__global__ void k_gc(const double* __restrict__ psum, const float* __restrict__ cnt,
                     float* __restrict__ gc, int B, int C) {
  int i = blockIdx.x * blockDim.x + threadIdx.x;
  if (i < B * C) {
    int b = i / C;
    gc[i] = (float)psum[i] * (1.f / fmaxf(cnt[b], 1.f));
  }
}

__global__ __launch_bounds__(256)
void k_fc1(const float* __restrict__ gc, const float* __restrict__ Wf1,
           const float* __restrict__ bf1, float* __restrict__ hidden,
           int C, int Hh) {
  const int b = blockIdx.y;
  const int j = blockIdx.x * 256 + threadIdx.x;
  if (j >= Hh) return;
  const float* g = gc + (size_t)b * C;
  const float* w = Wf1 + j;
  float a0 = 0.f, a1 = 0.f, a2 = 0.f, a3 = 0.f;
  int c = 0;
  for (; c + 4 <= C; c += 4) {
    a0 = fmaf(g[c + 0], w[(size_t)(c + 0) * Hh], a0);
    a1 = fmaf(g[c + 1], w[(size_t)(c + 1) * Hh], a1);
    a2 = fmaf(g[c + 2], w[(size_t)(c + 2) * Hh], a2);
    a3 = fmaf(g[c + 3], w[(size_t)(c + 3) * Hh], a3);
  }
  for (; c < C; c++) a0 = fmaf(g[c], w[(size_t)c * Hh], a0);
  float r = ((a0 + a1) + (a2 + a3)) + bf1[j];
  hidden[(size_t)b * Hh + j] = fmaxf(r, 0.f);
}

__global__ void k_fc2(const float* __restrict__ hidden, const float* __restrict__ Wf2,
                      const float* __restrict__ bf2, float* __restrict__ out, int Hh) {
  int b = blockIdx.x;
  int lane = threadIdx.x;  // 64
  double s = 0.0;
  for (int j = lane; j < Hh; j += 64) s += (double)hidden[(size_t)b * Hh + j] * (double)Wf2[j];
#pragma unroll
  for (int off = 32; off > 0; off >>= 1) s += __shfl_down(s, off);
  if (lane == 0) out[b] = (float)s + bf2[0];
}

// ================= launch =================

extern "C" void kernel_launch(void* const* d_in, const int* in_sizes, int n_in,
                              void* d_out, int out_size, void* d_ws, size_t ws_size,
                              hipStream_t stream) {
  const float* feature = (const float*)d_in[0];
  const int*   eidx    = (const int*)  d_in[1];
  const float* weight  = (const float*)d_in[2];
  const int*   pb      = (const int*)  d_in[3];
  const float* W1  = (const float*)d_in[4];
  const float* b1  = (const float*)d_in[5];
  const float* W2  = (const float*)d_in[6];
  const float* b2  = (const float*)d_in[7];
  const float* W3  = (const float*)d_in[8];
  const float* b3  = (const float*)d_in[9];
  const float* Wf1 = (const float*)d_in[10];
  const float* bf1 = (const float*)d_in[11];
  const float* Wf2 = (const float*)d_in[12];
  const float* bf2 = (const float*)d_in[13];

  const int F  = in_sizes[5];          // 64
  const int D2 = in_sizes[7];          // 128
  const int D3 = in_sizes[9];          // 256
  const int Hh = in_sizes[11];         // 1024
  const int N  = in_sizes[0] / F;      // 100000
  const int E  = in_sizes[1] / 2;      // 1200000
  const int B  = out_size;             // 256
  const int C  = D3 + F;               // 320

  const int* srcp = eidx;
  const int* dstp = eidx + E;
  const int nscan = (N + 1023) / 1024;

  auto al = [](size_t x) { return (x + 255) & ~(size_t)255; };
  size_t off = 0;
  auto alloc = [&](size_t bytes) { size_t o = off; off += al(bytes); return o; };
  size_t o_pack  = alloc((size_t)N * 8);
  size_t o_dinv  = alloc((size_t)N * 4);
  size_t o_sn    = alloc((size_t)N * 4);
  size_t o_rs    = alloc((size_t)N * 4);
  size_t o_rse   = alloc((size_t)N * 4);
  size_t o_fill  = alloc((size_t)N * 4);
  size_t o_bsum  = alloc((size_t)nscan * 4);
  size_t o_epack = alloc((size_t)E * 8);
  size_t o_featb = alloc((size_t)N * F  * 2);
  size_t o_x1b   = alloc((size_t)N * F  * 2);
  size_t o_x2b   = alloc((size_t)N * D2 * 2);
  size_t o_x3b   = alloc((size_t)N * D3 * 2);
  size_t o_aggh  = alloc((size_t)N * D2 * 2);   // bf16 hi (max K = 128)
  size_t o_aggl  = alloc((size_t)N * D2 * 2);   // bf16 lo
  size_t o_w1h   = alloc((size_t)F  * F  * 2);
  size_t o_w1l   = alloc((size_t)F  * F  * 2);
  size_t o_w2h   = alloc((size_t)F  * D2 * 2);
  size_t o_w2l   = alloc((size_t)F  * D2 * 2);
  size_t o_w3h   = alloc((size_t)D2 * D3 * 2);
  size_t o_w3l   = alloc((size_t)D2 * D3 * 2);
  size_t o_psum  = alloc((size_t)B * C * 8);
  size_t o_gc    = alloc((size_t)B * C * 4);
  size_t o_gcnt  = alloc((size_t)B * 4);
  size_t o_hid   = alloc((size_t)B * Hh * 4);
  if (off > ws_size) {
    fprintf(stderr, "kernel_launch: workspace too small: need %zu, have %zu\n", off, ws_size);
    return;
  }

  char* ws = (char*)d_ws;
  unsigned long long* packed = (unsigned long long*)(ws + o_pack);
  float*  dinv  = (float*)(ws + o_dinv);
  float*  sn    = (float*)(ws + o_sn);
  int*    rs    = (int*)  (ws + o_rs);
  int*    rse   = (int*)  (ws + o_rse);
  int*    fill  = (int*)  (ws + o_fill);
  int*    bsum  = (int*)  (ws + o_bsum);
  int2*   epack = (int2*) (ws + o_epack);
  ushort* featb = (ushort*)(ws + o_featb);
  ushort* x1b   = (ushort*)(ws + o_x1b);
  ushort* x2b   = (ushort*)(ws + o_x2b);
  ushort* x3b   = (ushort*)(ws + o_x3b);
  ushort* aggh  = (ushort*)(ws + o_aggh);
  ushort* aggl  = (ushort*)(ws + o_aggl);
  ushort* w1h   = (ushort*)(ws + o_w1h);
  ushort* w1l   = (ushort*)(ws + o_w1l);
  ushort* w2h   = (ushort*)(ws + o_w2h);
  ushort* w2l   = (ushort*)(ws + o_w2l);
  ushort* w3h   = (ushort*)(ws + o_w3h);
  ushort* w3l   = (ushort*)(ws + o_w3l);
  double* psum  = (double*)(ws + o_psum);
  float*  gcbuf = (float*)(ws + o_gc);
  float*  gcnt  = (float*)(ws + o_gcnt);
  float*  hid   = (float*)(ws + o_hid);
  float*  out   = (float*)d_out;

  // ---- pre-pass + CSR build + weight split ----
  k_init       <<<(N + 255) / 256, 256, 0, stream>>>(packed, fill, N);
  k_count_pack <<<(E + 255) / 256, 256, 0, stream>>>(dstp, weight, packed, E);
  k_dinv       <<<(N + 255) / 256, 256, 0, stream>>>(packed, dinv, sn, N);
  k_scan1      <<<nscan, 256, 0, stream>>>(packed, rs, bsum, N);
  k_scan2      <<<1, 64, 0, stream>>>(bsum, nscan);
  k_scan3      <<<(N + 255) / 256, 256, 0, stream>>>(rs, bsum, N);
  k_csr_fill   <<<(E + 255) / 256, 256, 0, stream>>>(srcp, dstp, weight, dinv, rs, fill, epack, E);
  k_rs_end     <<<(N + 255) / 256, 256, 0, stream>>>(rs, fill, rse, N);
  k_zero_pool  <<<(B * C + 255) / 256, 256, 0, stream>>>(psum, gcnt, B, C);
  k_tobf       <<<(N * F / 4 + 255) / 256, 256, 0, stream>>>(feature, featb, N * F);
  k_wsplit     <<<(F  * F  + 255) / 256, 256, 0, stream>>>(W1, w1h, w1l, F,  F);
  k_wsplit     <<<(F  * D2 + 255) / 256, 256, 0, stream>>>(W2, w2h, w2l, F,  D2);
  k_wsplit     <<<(D2 * D3 + 255) / 256, 256, 0, stream>>>(W3, w3h, w3l, D2, D3);

  const int gy = (N + 127) / 128;

  // ---- layer 1: agg(featb)[N,64] @ W1[64,64] -> x1b (bf16) ----
  {
    int tot = N * (F / 8);
    k_aggregate_b<3><<<(tot + 255) / 256, 256, 0, stream>>>(featb, rs, rse, epack, sn, aggh, aggl, N);
    dim3 g(1, gy);
    k_gemm_mfma<64, 64, 1><<<g, 256, 0, stream>>>(aggh, aggl, w1h, w1l, b1, x1b, N, F);
  }
  // ---- layer 2: agg(x1b)[N,64] @ W2[64,128] -> x2b (bf16) ----
  {
    int tot = N * (F / 8);
    k_aggregate_b<3><<<(tot + 255) / 256, 256, 0, stream>>>(x1b, rs, rse, epack, sn, aggh, aggl, N);
    dim3 g(1, gy);
    k_gemm_mfma<64, 128, 1><<<g, 256, 0, stream>>>(aggh, aggl, w2h, w2l, b2, x2b, N, D2);
  }
  // ---- layer 3: agg(x2b)[N,128] @ W3[128,256] -> x3b (bf16) ----
  {
    int tot = N * (D2 / 8);
    k_aggregate_b<4><<<(tot + 255) / 256, 256, 0, stream>>>(x2b, rs, rse, epack, sn, aggh, aggl, N);
    dim3 g(2, gy);
    k_gemm_mfma<128, 128, 1><<<g, 256, 0, stream>>>(aggh, aggl, w3h, w3l, b3, x3b, N, D3);
  }

  // ---- pooling + head ----
  k_count<<<((N + 63) / 64 + 255) / 256, 256, 0, stream>>>(pb, gcnt, N);
  k_pool <<<(N + 63) / 64, C, 0, stream>>>(x3b, feature, pb, psum, N, D3, F);
  k_gc   <<<(B * C + 255) / 256, 256, 0, stream>>>(psum, gcnt, gcbuf, B, C);
  {
    dim3 g((Hh + 255) / 256, B);
    k_fc1<<<g, 256, 0, stream>>>(gcbuf, Wf1, bf1, hid, C, Hh);
  }
  k_fc2  <<<B, 64, 0, stream>>>(hid, Wf2, bf2, out, Hh);
}

// Round 7
// 526.339 us; speedup vs baseline: 14.5310x; 1.0860x over previous
//
#include <hip/hip_runtime.h>
#include <cstdio>
#include <cstdint>

typedef short bf16x8 __attribute__((ext_vector_type(8)));
typedef float f32x4 __attribute__((ext_vector_type(4)));

__device__ inline unsigned short f2bf(float f) {  // fp32 -> bf16 RNE
  unsigned u = __float_as_uint(f);
  u += 0x7fffu + ((u >> 16) & 1u);
  return (unsigned short)(u >> 16);
}
__device__ inline float bf2f(unsigned short h) {
  return __uint_as_float(((unsigned)h) << 16);
}

// ================= pre-pass: degree, norms, CSR build =================
// packed[d]: high 24 bits = in-edge count, low 40 bits = sum(ew) in 2^-30
// fixed point (capacity 1024.0; quant error ~1e-9 relative on deg).
// The returning atomic's old value >> 40 is this edge's rank within its
// dst row -> csr_fill needs no second atomic.

__global__ void k_init(unsigned long long* __restrict__ packed, int N) {
  int i = blockIdx.x * blockDim.x + threadIdx.x;
  if (i < N) packed[i] = 0ull;
}

__global__ void k_count_pack(const int* __restrict__ dst, const float* __restrict__ ew,
                             unsigned long long* __restrict__ packed,
                             int* __restrict__ rank, int E) {
  int e = blockIdx.x * blockDim.x + threadIdx.x;
  if (e < E) {
    unsigned long long q = (unsigned long long)(ew[e] * 1073741824.0f + 0.5f);
    unsigned long long old = atomicAdd(&packed[dst[e]], (1ull << 40) | q);
    rank[e] = (int)(old >> 40);
  }
}

__global__ void k_dinv(const unsigned long long* __restrict__ packed,
                       float* __restrict__ dinv, float* __restrict__ selfnorm, int N) {
  int i = blockIdx.x * blockDim.x + threadIdx.x;
  if (i < N) {
    unsigned long long p = packed[i];
    double deg = 1.0 + (double)(p & 0xFFFFFFFFFFull) * (1.0 / 1073741824.0);
    float r = (float)(1.0 / sqrt(deg));   // deg >= 1 always (self-loop)
    dinv[i] = r;
    selfnorm[i] = r * r;
  }
}

// exclusive scan of cnt (= packed>>40) -> rs[N]; 1024 elems / block
__global__ __launch_bounds__(256)
void k_scan1(const unsigned long long* __restrict__ packed, int* __restrict__ rs,
             int* __restrict__ bsum, int N) {
  __shared__ int sh[256];
  const int t = threadIdx.x;
  const int base = blockIdx.x * 1024;
  int v[4]; int s = 0;
#pragma unroll
  for (int j = 0; j < 4; j++) {
    int idx = base + t * 4 + j;
    v[j] = (idx < N) ? (int)(packed[idx] >> 40) : 0;
    s += v[j];
  }
  sh[t] = s;
  __syncthreads();
  for (int off = 1; off < 256; off <<= 1) {
    int x = (t >= off) ? sh[t - off] : 0;
    __syncthreads();
    sh[t] += x;
    __syncthreads();
  }
  int run = sh[t] - s;
#pragma unroll
  for (int j = 0; j < 4; j++) {
    int idx = base + t * 4 + j;
    if (idx < N) rs[idx] = run;
    run += v[j];
  }
  if (t == 255) bsum[blockIdx.x] = sh[255];
}

__global__ void k_scan2(int* __restrict__ bsum, int nb) {
  if (blockIdx.x == 0 && threadIdx.x == 0) {
    int run = 0;
    for (int i = 0; i < nb; i++) { int v = bsum[i]; bsum[i] = run; run += v; }
  }
}

__global__ void k_scan3(int* __restrict__ rs, const int* __restrict__ bsum, int N, int E) {
  int i = blockIdx.x * blockDim.x + threadIdx.x;
  if (i < N) rs[i] += bsum[i >> 10];
  if (i == 0) rs[N] = E;   // row-end sentinel
}

// no atomics: pos = rs[dst] + rank (rank captured in k_count_pack)
__global__ void k_csr_fill(const int* __restrict__ src, const int* __restrict__ dst,
                           const float* __restrict__ ew, const float* __restrict__ dinv,
                           const int* __restrict__ rs, const int* __restrict__ rank,
                           int2* __restrict__ epack, int E) {
  int e = blockIdx.x * blockDim.x + threadIdx.x;
  if (e >= E) return;
  int d = dst[e], s = src[e];
  int pos = rs[d] + rank[e];
  float w = dinv[s] * ew[e] * dinv[d];
  epack[pos] = make_int2(s, __float_as_int(w));
}

__global__ void k_zero_pool(double* __restrict__ psum, float* __restrict__ cnt, int B, int C) {
  int i = blockIdx.x * blockDim.x + threadIdx.x;
  if (i < B * C) psum[i] = 0.0;
  if (i < B) cnt[i] = 0.f;
}

// split W [K][D] fp32 -> transposed bf16 hi/lo [D][K]
__global__ void k_wsplit(const float* __restrict__ W, ushort* __restrict__ Th,
                         ushort* __restrict__ Tl, int K, int D) {
  int i = blockIdx.x * blockDim.x + threadIdx.x;
  if (i >= K * D) return;
  int k = i / D, n = i - k * D;
  float f = W[i];
  ushort h = f2bf(f);
  Th[(size_t)n * K + k] = h;
  Tl[(size_t)n * K + k] = f2bf(f - bf2f(h));
}

// fp32 -> bf16 (RNE), 4 elems/thread
__global__ void k_tobf(const float* __restrict__ X, ushort* __restrict__ Y, int n) {
  int base = (blockIdx.x * blockDim.x + threadIdx.x) * 4;
  if (base < n) {
    float4 v = *reinterpret_cast<const float4*>(X + base);
    ushort4 h;
    h.x = f2bf(v.x); h.y = f2bf(v.y); h.z = f2bf(v.z); h.w = f2bf(v.w);
    *reinterpret_cast<ushort4*>(Y + base) = h;
  }
}

// ================= CSR gather aggregation (bf16 in, bf16 hi/lo out) ======
// lanes/row = D/8; each lane handles 8 cols via one 16B load per gather.
// Edge loop unrolled x2 via int4 epack loads (two independent gathers in
// flight per iteration).

__device__ inline void bf8_fma(const int4 v, float w, float* acc) {
  acc[0] = fmaf(__uint_as_float((unsigned)v.x << 16), w, acc[0]);
  acc[1] = fmaf(__uint_as_float((unsigned)v.x & 0xffff0000u), w, acc[1]);
  acc[2] = fmaf(__uint_as_float((unsigned)v.y << 16), w, acc[2]);
  acc[3] = fmaf(__uint_as_float((unsigned)v.y & 0xffff0000u), w, acc[3]);
  acc[4] = fmaf(__uint_as_float((unsigned)v.z << 16), w, acc[4]);
  acc[5] = fmaf(__uint_as_float((unsigned)v.z & 0xffff0000u), w, acc[5]);
  acc[6] = fmaf(__uint_as_float((unsigned)v.w << 16), w, acc[6]);
  acc[7] = fmaf(__uint_as_float((unsigned)v.w & 0xffff0000u), w, acc[7]);
}

template<int LOG2L>
__global__ __launch_bounds__(256)
void k_aggregate_b(const ushort* __restrict__ Xb, const int* __restrict__ rs,
                   const int2* __restrict__ epack, const float* __restrict__ sn,
                   ushort* __restrict__ AH, ushort* __restrict__ AL, int N) {
  const int t = blockIdx.x * blockDim.x + threadIdx.x;
  const int row = t >> LOG2L;
  if (row >= N) return;
  const int L = 1 << LOG2L;
  const int D = L << 3;
  const int c = (t & (L - 1)) << 3;

  float acc[8];
  {
    int4 v = *reinterpret_cast<const int4*>(Xb + (size_t)row * D + c);
    float s = sn[row];
    acc[0] = s * __uint_as_float((unsigned)v.x << 16);
    acc[1] = s * __uint_as_float((unsigned)v.x & 0xffff0000u);
    acc[2] = s * __uint_as_float((unsigned)v.y << 16);
    acc[3] = s * __uint_as_float((unsigned)v.y & 0xffff0000u);
    acc[4] = s * __uint_as_float((unsigned)v.z << 16);
    acc[5] = s * __uint_as_float((unsigned)v.z & 0xffff0000u);
    acc[6] = s * __uint_as_float((unsigned)v.w << 16);
    acc[7] = s * __uint_as_float((unsigned)v.w & 0xffff0000u);
  }
  const int p0 = rs[row], pe = rs[row + 1];
  int i = p0;
  if ((i & 1) && i < pe) {   // peel to 16B-aligned pair index
    int2 e = epack[i];
    int4 v = *reinterpret_cast<const int4*>(Xb + (size_t)e.x * D + c);
    bf8_fma(v, __int_as_float(e.y), acc);
    i++;
  }
  for (; i + 2 <= pe; i += 2) {
    int4 e2 = *reinterpret_cast<const int4*>(&epack[i]);
    int4 v0 = *reinterpret_cast<const int4*>(Xb + (size_t)e2.x * D + c);
    int4 v1 = *reinterpret_cast<const int4*>(Xb + (size_t)e2.z * D + c);
    bf8_fma(v0, __int_as_float(e2.y), acc);
    bf8_fma(v1, __int_as_float(e2.w), acc);
  }
  if (i < pe) {
    int2 e = epack[i];
    int4 v = *reinterpret_cast<const int4*>(Xb + (size_t)e.x * D + c);
    bf8_fma(v, __int_as_float(e.y), acc);
  }
  ushort h[8], l[8];
#pragma unroll
  for (int j = 0; j < 8; j++) {
    h[j] = f2bf(acc[j]);
    l[j] = f2bf(acc[j] - bf2f(h[j]));
  }
  size_t o = (size_t)row * D + c;
  *reinterpret_cast<ushort4*>(AH + o)     = make_ushort4(h[0], h[1], h[2], h[3]);
  *reinterpret_cast<ushort4*>(AH + o + 4) = make_ushort4(h[4], h[5], h[6], h[7]);
  *reinterpret_cast<ushort4*>(AL + o)     = make_ushort4(l[0], l[1], l[2], l[3]);
  *reinterpret_cast<ushort4*>(AL + o + 4) = make_ushort4(l[4], l[5], l[6], l[7]);
}

// ================= split-bf16 MFMA GEMM: Y = relu(A @ W + b) =================
// OUTBF=1: write bf16; OUTBF=0: write fp32.

template<int KT, int NT, int OUTBF>
__global__ __launch_bounds__(256)
void k_gemm_mfma(const ushort* __restrict__ Ah, const ushort* __restrict__ Al,
                 const ushort* __restrict__ Bh, const ushort* __restrict__ Bl,
                 const float* __restrict__ bias, void* __restrict__ Yv,
                 int N, int D) {
  constexpr int PK = 72;  // padded row length (bf16) -> <=2-way LDS aliasing
  __shared__ __align__(16) ushort sAh[128 * PK];
  __shared__ __align__(16) ushort sAl[128 * PK];
  __shared__ __align__(16) ushort sBh[NT * PK];
  __shared__ __align__(16) ushort sBl[NT * PK];
  const int t = threadIdx.x;
  const int wave = t >> 6, lane = t & 63;
  const int quad = lane >> 4, l16 = lane & 15;
  const int m0 = blockIdx.y * 128;
  const int n0 = blockIdx.x * NT;

  f32x4 acc[2][NT / 16];
#pragma unroll
  for (int mi = 0; mi < 2; mi++)
#pragma unroll
    for (int ni = 0; ni < NT / 16; ni++) acc[mi][ni] = (f32x4){0.f, 0.f, 0.f, 0.f};

  for (int k0 = 0; k0 < KT; k0 += 64) {
    if (k0) __syncthreads();
#pragma unroll
    for (int it = 0; it < 4; it++) {
      int c = t + 256 * it;
      int row = c >> 3, kc = (c & 7) << 3;
      int gr = m0 + row; if (gr >= N) gr = N - 1;
      size_t gofs = (size_t)gr * KT + k0 + kc;
      *reinterpret_cast<int4*>(&sAh[row * PK + kc]) = *reinterpret_cast<const int4*>(Ah + gofs);
      *reinterpret_cast<int4*>(&sAl[row * PK + kc]) = *reinterpret_cast<const int4*>(Al + gofs);
    }
#pragma unroll
    for (int it = 0; it < NT / 32; it++) {
      int c = t + 256 * it;
      int row = c >> 3, kc = (c & 7) << 3;
      size_t gofs = (size_t)(n0 + row) * KT + k0 + kc;
      *reinterpret_cast<int4*>(&sBh[row * PK + kc]) = *reinterpret_cast<const int4*>(Bh + gofs);
      *reinterpret_cast<int4*>(&sBl[row * PK + kc]) = *reinterpret_cast<const int4*>(Bl + gofs);
    }
    __syncthreads();
#pragma unroll
    for (int ks = 0; ks < 2; ks++) {
      const int kk = ks * 32 + quad * 8;
      bf16x8 aH[2], aL[2];
#pragma unroll
      for (int mi = 0; mi < 2; mi++) {
        int r = wave * 32 + mi * 16 + l16;
        aH[mi] = *reinterpret_cast<const bf16x8*>(&sAh[r * PK + kk]);
        aL[mi] = *reinterpret_cast<const bf16x8*>(&sAl[r * PK + kk]);
      }
#pragma unroll
      for (int ni = 0; ni < NT / 16; ni++) {
        int r = ni * 16 + l16;
        bf16x8 bH = *reinterpret_cast<const bf16x8*>(&sBh[r * PK + kk]);
        bf16x8 bL = *reinterpret_cast<const bf16x8*>(&sBl[r * PK + kk]);
#pragma unroll
        for (int mi = 0; mi < 2; mi++) {
          acc[mi][ni] = __builtin_amdgcn_mfma_f32_16x16x32_bf16(aH[mi], bH, acc[mi][ni], 0, 0, 0);
          acc[mi][ni] = __builtin_amdgcn_mfma_f32_16x16x32_bf16(aH[mi], bL, acc[mi][ni], 0, 0, 0);
          acc[mi][ni] = __builtin_amdgcn_mfma_f32_16x16x32_bf16(aL[mi], bH, acc[mi][ni], 0, 0, 0);
        }
      }
    }
  }
  // epilogue: C/D layout col=lane&15, row=quad*4+reg
#pragma unroll
  for (int mi = 0; mi < 2; mi++) {
    int rb = m0 + wave * 32 + mi * 16 + quad * 4;
#pragma unroll
    for (int ni = 0; ni < NT / 16; ni++) {
      int col = n0 + ni * 16 + l16;
      float bv = bias[col];
#pragma unroll
      for (int r = 0; r < 4; r++) {
        int row = rb + r;
        if (row < N) {
          float y = fmaxf(acc[mi][ni][r] + bv, 0.f);
          if (OUTBF) ((ushort*)Yv)[(size_t)row * D + col] = f2bf(y);
          else       ((float*) Yv)[(size_t)row * D + col] = y;
        }
      }
    }
  }
}

// ================= pooling (sorted protein_batch) =================

__global__ void k_pool(const ushort* __restrict__ X3b, const float* __restrict__ feat,
                       const int* __restrict__ pb, double* __restrict__ psum,
                       int N, int D3, int F) {
  const int c = threadIdx.x;
  const int C = D3 + F;
  int i0 = blockIdx.x * 64;
  if (i0 >= N) return;
  int iend = i0 + 64; if (iend > N) iend = N;
  double acc = 0.0;
  int cur = pb[i0];
  for (int i = i0; i < iend; i++) {
    int b = pb[i];
    if (b != cur) {
      atomicAdd(&psum[(size_t)cur * C + c], acc);
      acc = 0.0; cur = b;
    }
    float v;
    if (c < D3) v = bf2f(X3b[(size_t)i * D3 + c]);
    else        v = feat[(size_t)i * F + (c - D3)];
    acc += (double)v;
  }
  atomicAdd(&psum[(size_t)cur * C + c], acc);
}

__global__ void k_count(const int* __restrict__ pb, float* __restrict__ cnt, int N) {
  int tchunk = blockIdx.x * blockDim.x + threadIdx.x;
  int i0 = tchunk * 64;
  if (i0 >= N) return;
  int iend = i0 + 64; if (iend > N) iend = N;
  float cacc = 0.f; int cur = pb[i0];
  for (int i = i0; i < iend; i++) {
    int b = pb[i];
    if (b != cur) { atomicAdd(&cnt[cur], cacc); cacc = 0.f; cur = b; }
    cacc += 1.f;
  }
  atomicAdd(&cnt[cur], cacc);
}

// ================= FC head =================

__global__ void k_gc(const double* __restrict__ psum, const float* __restrict__ cnt,
                     float* __restrict__ gc, int B, int C) {
  int i = blockIdx.x * blockDim.x + threadIdx.x;
  if (i < B * C) {
    int b = i / C;
    gc[i] = (float)psum[i] * (1.f / fmaxf(cnt[b], 1.f));
  }
}

__global__ __launch_bounds__(256)
void k_fc1(const float* __restrict__ gc, const float* __restrict__ Wf1,
           const float* __restrict__ bf1, float* __restrict__ hidden,
           int C, int Hh) {
  const int b = blockIdx.y;
  const int j = blockIdx.x * 256 + threadIdx.x;
  if (j >= Hh) return;
  const float* g = gc + (size_t)b * C;
  const float* w = Wf1 + j;
  float a0 = 0.f, a1 = 0.f, a2 = 0.f, a3 = 0.f;
  int c = 0;
  for (; c + 4 <= C; c += 4) {
    a0 = fmaf(g[c + 0], w[(size_t)(c + 0) * Hh], a0);
    a1 = fmaf(g[c + 1], w[(size_t)(c + 1) * Hh], a1);
    a2 = fmaf(g[c + 2], w[(size_t)(c + 2) * Hh], a2);
    a3 = fmaf(g[c + 3], w[(size_t)(c + 3) * Hh], a3);
  }
  for (; c < C; c++) a0 = fmaf(g[c], w[(size_t)c * Hh], a0);
  float r = ((a0 + a1) + (a2 + a3)) + bf1[j];
  hidden[(size_t)b * Hh + j] = fmaxf(r, 0.f);
}

__global__ void k_fc2(const float* __restrict__ hidden, const float* __restrict__ Wf2,
                      const float* __restrict__ bf2, float* __restrict__ out, int Hh) {
  int b = blockIdx.x;
  int lane = threadIdx.x;  // 64
  double s = 0.0;
  for (int j = lane; j < Hh; j += 64) s += (double)hidden[(size_t)b * Hh + j] * (double)Wf2[j];
#pragma unroll
  for (int off = 32; off > 0; off >>= 1) s += __shfl_down(s, off);
  if (lane == 0) out[b] = (float)s + bf2[0];
}

// ================= launch =================

extern "C" void kernel_launch(void* const* d_in, const int* in_sizes, int n_in,
                              void* d_out, int out_size, void* d_ws, size_t ws_size,
                              hipStream_t stream) {
  const float* feature = (const float*)d_in[0];
  const int*   eidx    = (const int*)  d_in[1];
  const float* weight  = (const float*)d_in[2];
  const int*   pb      = (const int*)  d_in[3];
  const float* W1  = (const float*)d_in[4];
  const float* b1  = (const float*)d_in[5];
  const float* W2  = (const float*)d_in[6];
  const float* b2  = (const float*)d_in[7];
  const float* W3  = (const float*)d_in[8];
  const float* b3  = (const float*)d_in[9];
  const float* Wf1 = (const float*)d_in[10];
  const float* bf1 = (const float*)d_in[11];
  const float* Wf2 = (const float*)d_in[12];
  const float* bf2 = (const float*)d_in[13];

  const int F  = in_sizes[5];          // 64
  const int D2 = in_sizes[7];          // 128
  const int D3 = in_sizes[9];          // 256
  const int Hh = in_sizes[11];         // 1024
  const int N  = in_sizes[0] / F;      // 100000
  const int E  = in_sizes[1] / 2;      // 1200000
  const int B  = out_size;             // 256
  const int C  = D3 + F;               // 320

  const int* srcp = eidx;
  const int* dstp = eidx + E;
  const int nscan = (N + 1023) / 1024;

  auto al = [](size_t x) { return (x + 255) & ~(size_t)255; };
  size_t off = 0;
  auto alloc = [&](size_t bytes) { size_t o = off; off += al(bytes); return o; };
  size_t o_pack  = alloc((size_t)N * 8);
  size_t o_dinv  = alloc((size_t)N * 4);
  size_t o_sn    = alloc((size_t)N * 4);
  size_t o_rs    = alloc((size_t)(N + 1) * 4);
  size_t o_rank  = alloc((size_t)E * 4);
  size_t o_bsum  = alloc((size_t)nscan * 4);
  size_t o_epack = alloc((size_t)E * 8);
  size_t o_featb = alloc((size_t)N * F  * 2);
  size_t o_x1b   = alloc((size_t)N * F  * 2);
  size_t o_x2b   = alloc((size_t)N * D2 * 2);
  size_t o_x3b   = alloc((size_t)N * D3 * 2);
  size_t o_aggh  = alloc((size_t)N * D2 * 2);   // bf16 hi (max K = 128)
  size_t o_aggl  = alloc((size_t)N * D2 * 2);   // bf16 lo
  size_t o_w1h   = alloc((size_t)F  * F  * 2);
  size_t o_w1l   = alloc((size_t)F  * F  * 2);
  size_t o_w2h   = alloc((size_t)F  * D2 * 2);
  size_t o_w2l   = alloc((size_t)F  * D2 * 2);
  size_t o_w3h   = alloc((size_t)D2 * D3 * 2);
  size_t o_w3l   = alloc((size_t)D2 * D3 * 2);
  size_t o_psum  = alloc((size_t)B * C * 8);
  size_t o_gc    = alloc((size_t)B * C * 4);
  size_t o_gcnt  = alloc((size_t)B * 4);
  size_t o_hid   = alloc((size_t)B * Hh * 4);
  if (off > ws_size) {
    fprintf(stderr, "kernel_launch: workspace too small: need %zu, have %zu\n", off, ws_size);
    return;
  }

  char* ws = (char*)d_ws;
  unsigned long long* packed = (unsigned long long*)(ws + o_pack);
  float*  dinv  = (float*)(ws + o_dinv);
  float*  sn    = (float*)(ws + o_sn);
  int*    rs    = (int*)  (ws + o_rs);
  int*    rank  = (int*)  (ws + o_rank);
  int*    bsum  = (int*)  (ws + o_bsum);
  int2*   epack = (int2*) (ws + o_epack);
  ushort* featb = (ushort*)(ws + o_featb);
  ushort* x1b   = (ushort*)(ws + o_x1b);
  ushort* x2b   = (ushort*)(ws + o_x2b);
  ushort* x3b   = (ushort*)(ws + o_x3b);
  ushort* aggh  = (ushort*)(ws + o_aggh);
  ushort* aggl  = (ushort*)(ws + o_aggl);
  ushort* w1h   = (ushort*)(ws + o_w1h);
  ushort* w1l   = (ushort*)(ws + o_w1l);
  ushort* w2h   = (ushort*)(ws + o_w2h);
  ushort* w2l   = (ushort*)(ws + o_w2l);
  ushort* w3h   = (ushort*)(ws + o_w3h);
  ushort* w3l   = (ushort*)(ws + o_w3l);
  double* psum  = (double*)(ws + o_psum);
  float*  gcbuf = (float*)(ws + o_gc);
  float*  gcnt  = (float*)(ws + o_gcnt);
  float*  hid   = (float*)(ws + o_hid);
  float*  out   = (float*)d_out;

  // ---- pre-pass + CSR build + weight split ----
  k_init       <<<(N + 255) / 256, 256, 0, stream>>>(packed, N);
  k_count_pack <<<(E + 255) / 256, 256, 0, stream>>>(dstp, weight, packed, rank, E);
  k_dinv       <<<(N + 255) / 256, 256, 0, stream>>>(packed, dinv, sn, N);
  k_scan1      <<<nscan, 256, 0, stream>>>(packed, rs, bsum, N);
  k_scan2      <<<1, 64, 0, stream>>>(bsum, nscan);
  k_scan3      <<<(N + 255) / 256, 256, 0, stream>>>(rs, bsum, N, E);
  k_csr_fill   <<<(E + 255) / 256, 256, 0, stream>>>(srcp, dstp, weight, dinv, rs, rank, epack, E);
  k_zero_pool  <<<(B * C + 255) / 256, 256, 0, stream>>>(psum, gcnt, B, C);
  k_tobf       <<<(N * F / 4 + 255) / 256, 256, 0, stream>>>(feature, featb, N * F);
  k_wsplit     <<<(F  * F  + 255) / 256, 256, 0, stream>>>(W1, w1h, w1l, F,  F);
  k_wsplit     <<<(F  * D2 + 255) / 256, 256, 0, stream>>>(W2, w2h, w2l, F,  D2);
  k_wsplit     <<<(D2 * D3 + 255) / 256, 256, 0, stream>>>(W3, w3h, w3l, D2, D3);

  const int gy = (N + 127) / 128;

  // ---- layer 1: agg(featb)[N,64] @ W1[64,64] -> x1b (bf16) ----
  {
    int tot = N * (F / 8);
    k_aggregate_b<3><<<(tot + 255) / 256, 256, 0, stream>>>(featb, rs, epack, sn, aggh, aggl, N);
    dim3 g(1, gy);
    k_gemm_mfma<64, 64, 1><<<g, 256, 0, stream>>>(aggh, aggl, w1h, w1l, b1, x1b, N, F);
  }
  // ---- layer 2: agg(x1b)[N,64] @ W2[64,128] -> x2b (bf16) ----
  {
    int tot = N * (F / 8);
    k_aggregate_b<3><<<(tot + 255) / 256, 256, 0, stream>>>(x1b, rs, epack, sn, aggh, aggl, N);
    dim3 g(1, gy);
    k_gemm_mfma<64, 128, 1><<<g, 256, 0, stream>>>(aggh, aggl, w2h, w2l, b2, x2b, N, D2);
  }
  // ---- layer 3: agg(x2b)[N,128] @ W3[128,256] -> x3b (bf16) ----
  {
    int tot = N * (D2 / 8);
    k_aggregate_b<4><<<(tot + 255) / 256, 256, 0, stream>>>(x2b, rs, epack, sn, aggh, aggl, N);
    dim3 g(2, gy);
    k_gemm_mfma<128, 128, 1><<<g, 256, 0, stream>>>(aggh, aggl, w3h, w3l, b3, x3b, N, D3);
  }

  // ---- pooling + head ----
  k_count<<<((N + 63) / 64 + 255) / 256, 256, 0, stream>>>(pb, gcnt, N);
  k_pool <<<(N + 63) / 64, C, 0, stream>>>(x3b, feature, pb, psum, N, D3, F);
  k_gc   <<<(B * C + 255) / 256, 256, 0, stream>>>(psum, gcnt, gcbuf, B, C);
  {
    dim3 g((Hh + 255) / 256, B);
    k_fc1<<<g, 256, 0, stream>>>(gcbuf, Wf1, bf1, hid, C, Hh);
  }
  k_fc2  <<<B, 64, 0, stream>>>(hid, Wf2, bf2, out, Hh);
}